// Round 8
// baseline (436.324 us; speedup 1.0000x reference)
//
#include <hip/hip_runtime.h>
#include <cstdint>
#include <cstddef>

typedef unsigned short US;
typedef __bf16 bf16_t;
typedef bf16_t bf16x8 __attribute__((ext_vector_type(8)));
typedef float  f32x4  __attribute__((ext_vector_type(4)));
typedef US     us8    __attribute__((ext_vector_type(8)));
typedef US     us4    __attribute__((ext_vector_type(4)));

#define AS1 __attribute__((address_space(1)))
#define AS3 __attribute__((address_space(3)))

__device__ __forceinline__ void gl_lds16(const void* g, void* l) {
    __builtin_amdgcn_global_load_lds((AS1 unsigned int*)(size_t)g,
                                     (AS3 unsigned int*)l, 16, 0, 0);
}

__device__ __forceinline__ US f2bf(float f) {
    unsigned u = __builtin_bit_cast(unsigned, f);
    u += 0x7FFFu + ((u >> 16) & 1u);   // RNE (inputs finite)
    return (US)(u >> 16);
}

__device__ __forceinline__ float bf2f(US u) {
    return __builtin_bit_cast(float, (unsigned)u << 16);
}

__device__ __forceinline__ bf16x8 ldv8(const US* p) {
    return __builtin_bit_cast(bf16x8, *(const us8*)p);
}

// ---------------- prep: X converts + mask bits + weight transposes (4096 fat blocks) ----
// All roles are HBM-streaming (no reuse) so fusing them is L2-safe (round-6 lesson:
// never fuse streaming with GEMMs). Grid-stride units avoid tiny-block dispatch cost.
__global__ void prep(const float* __restrict__ Xq, const float* __restrict__ Xkv,
                     const int* __restrict__ Mi, unsigned long long* __restrict__ MBits,
                     US* __restrict__ XqB, US* __restrict__ XkvB,
                     const float* __restrict__ Wq, const float* __restrict__ Wk,
                     const float* __restrict__ Wv, const float* __restrict__ Wo,
                     US* __restrict__ WTbase) {
    __shared__ float t[32][33];
    const int b = blockIdx.x, tid = threadIdx.x;

    for (int u = b; u < 18432; u += 4096) {
        if (u < 2048) {
            int i = u * 256 + tid;
            float4 f = ((const float4*)Xq)[i];
            us4 o = { f2bf(f.x), f2bf(f.y), f2bf(f.z), f2bf(f.w) };
            ((us4*)XqB)[i] = o;
        } else {
            int i = (u - 2048) * 256 + tid;
            float4 f = ((const float4*)Xkv)[i];
            us4 o = { f2bf(f.x), f2bf(f.y), f2bf(f.z), f2bf(f.w) };
            ((us4*)XkvB)[i] = o;
        }
    }

    for (int u = b; u < 32768; u += 4096) {
        int i = u * 256 + tid;
        int m = Mi[i];
        unsigned long long bits = __ballot(m != 0);
        if ((tid & 63) == 0) MBits[i >> 6] = bits;
    }

    {
        int z = b >> 10, rr = b & 1023;
        int bx = rr & 31, by = rr >> 5;
        const float* W = (z == 0) ? Wq : (z == 1) ? Wk : (z == 2) ? Wv : Wo;
        US* WT = WTbase + (size_t)z * 1024 * 1024;
        int tx = tid & 31, ty = tid >> 5;
        int x = bx * 32 + tx;
#pragma unroll
        for (int r = 0; r < 4; ++r)
            t[ty + r * 8][tx] = W[(size_t)(by * 32 + ty + r * 8) * 1024 + x];
        __syncthreads();
        int nx = by * 32 + tx;
#pragma unroll
        for (int r = 0; r < 4; ++r)
            WT[(size_t)(bx * 32 + ty + r * 8) * 1024 + nx] = f2bf(t[tx][ty + r * 8]);
    }
}

// ---------------- GEMM: C[M,1024] = A[M,1024]bf16 @ Bt[1024,1024]^T + bias ----------------
template <int MODE, int BM>
__global__ __launch_bounds__(256, 2)
void gemm_bt(const US* __restrict__ A, const US* __restrict__ Bt,
             const float* __restrict__ bias, void* __restrict__ out,
             int tlog2, float scale) {
    constexpr int K = 1024, N = 1024, BK = 64;
    constexpr int MI = BM / 32;
    __shared__ US As[BM * BK];
    __shared__ US Bs[128 * BK];
    const int tid = threadIdx.x;
    const int wv = tid >> 6, ln = tid & 63;
    const int g = ln >> 4, c15 = ln & 15;
    const int m0 = blockIdx.x * BM, n0 = blockIdx.y * 128;
    const int wm = (wv & 1) * (BM / 2), wn = (wv >> 1) * 64;

    f32x4 acc[MI][4];
    const f32x4 z = {0.f, 0.f, 0.f, 0.f};
#pragma unroll
    for (int i = 0; i < MI; ++i)
#pragma unroll
        for (int j = 0; j < 4; ++j) acc[i][j] = z;

    const US* Ab = A + (size_t)m0 * K;
    const US* Bb = Bt + (size_t)n0 * K;

    for (int k0 = 0; k0 < K; k0 += BK) {
        __syncthreads();
#pragma unroll
        for (int q = 0; q < BM / 32; ++q) {
            int eb = (q * 256 + wv * 64) * 8;
            int r = (eb >> 6) + (ln >> 3);
            int sw = (ln & 7) ^ (r & 7);
            gl_lds16(Ab + (size_t)r * K + k0 + sw * 8, &As[eb]);
        }
#pragma unroll
        for (int q = 0; q < 4; ++q) {
            int eb = (q * 256 + wv * 64) * 8;
            int r = (eb >> 6) + (ln >> 3);
            int sw = (ln & 7) ^ (r & 7);
            gl_lds16(Bb + (size_t)r * K + k0 + sw * 8, &Bs[eb]);
        }
        __syncthreads();
#pragma unroll
        for (int ks = 0; ks < 2; ++ks) {
            bf16x8 a[MI], b[4];
#pragma unroll
            for (int i = 0; i < MI; ++i) {
                int p = (ks * 4 + g) ^ (c15 & 7);
                a[i] = ldv8(&As[(wm + i * 16 + c15) * BK + p * 8]);
            }
#pragma unroll
            for (int j = 0; j < 4; ++j) {
                int p = (ks * 4 + g) ^ (c15 & 7);
                b[j] = ldv8(&Bs[(wn + j * 16 + c15) * BK + p * 8]);
            }
#pragma unroll
            for (int i = 0; i < MI; ++i)
#pragma unroll
                for (int j = 0; j < 4; ++j)
                    acc[i][j] = __builtin_amdgcn_mfma_f32_16x16x32_bf16(a[i], b[j], acc[i][j], 0, 0, 0);
        }
    }

#pragma unroll
    for (int i = 0; i < MI; ++i) {
#pragma unroll
        for (int j = 0; j < 4; ++j) {
            int col = n0 + wn + j * 16 + c15;
            float bvv = bias[col];
#pragma unroll
            for (int r = 0; r < 4; ++r) {
                int row = m0 + wm + i * 16 + g * 4 + r;
                float v = (acc[i][j][r] + bvv) * scale;
                if (MODE == 0) {
                    int b_ = row >> tlog2;
                    int t = row & ((1 << tlog2) - 1);
                    int h = col >> 7, d = col & 127;
                    ((US*)out)[(((size_t)(b_ * 8 + h) << tlog2) + t) * 128 + d] = f2bf(v);
                } else {
                    ((float*)out)[(size_t)row * N + col] = v;
                }
            }
        }
    }
}

// ---------------- fused K+V projection GEMM; V written pre-transposed ----------------
__global__ __launch_bounds__(256, 2)
void gemm_kv(const US* __restrict__ A, const US* __restrict__ BtK,
             const US* __restrict__ BtV, const float* __restrict__ bk,
             const float* __restrict__ bv, US* __restrict__ Kout,
             US* __restrict__ VTout) {
    constexpr int K = 1024, BK = 64;
    __shared__ US lds[3 * 128 * BK];
    US* As  = lds;
    US* BsK = lds + 128 * BK;
    US* BsV = lds + 2 * 128 * BK;
    const int tid = threadIdx.x;
    const int wv = tid >> 6, ln = tid & 63;
    const int g = ln >> 4, c15 = ln & 15;
    const int m0 = blockIdx.x * 128, n0 = blockIdx.y * 128;
    const int wm = (wv & 1) * 64, wn = (wv >> 1) * 64;

    f32x4 aK[4][4], aV[4][4];
    const f32x4 z = {0.f, 0.f, 0.f, 0.f};
#pragma unroll
    for (int i = 0; i < 4; ++i)
#pragma unroll
        for (int j = 0; j < 4; ++j) { aK[i][j] = z; aV[i][j] = z; }

    const US* Ab  = A   + (size_t)m0 * K;
    const US* BbK = BtK + (size_t)n0 * K;
    const US* BbV = BtV + (size_t)n0 * K;

    for (int k0 = 0; k0 < K; k0 += BK) {
        __syncthreads();
#pragma unroll
        for (int q = 0; q < 4; ++q) {
            int eb = (q * 256 + wv * 64) * 8;
            int r = (eb >> 6) + (ln >> 3);
            int sw = (ln & 7) ^ (r & 7);
            gl_lds16(Ab  + (size_t)r * K + k0 + sw * 8, &As[eb]);
            gl_lds16(BbK + (size_t)r * K + k0 + sw * 8, &BsK[eb]);
            gl_lds16(BbV + (size_t)r * K + k0 + sw * 8, &BsV[eb]);
        }
        __syncthreads();
#pragma unroll
        for (int ks = 0; ks < 2; ++ks) {
            bf16x8 a[4], bK[4], bV[4];
#pragma unroll
            for (int i = 0; i < 4; ++i) {
                int p = (ks * 4 + g) ^ (c15 & 7);
                a[i] = ldv8(&As[(wm + i * 16 + c15) * BK + p * 8]);
            }
#pragma unroll
            for (int j = 0; j < 4; ++j) {
                int p = (ks * 4 + g) ^ (c15 & 7);
                bK[j] = ldv8(&BsK[(wn + j * 16 + c15) * BK + p * 8]);
                bV[j] = ldv8(&BsV[(wn + j * 16 + c15) * BK + p * 8]);
            }
#pragma unroll
            for (int i = 0; i < 4; ++i)
#pragma unroll
                for (int j = 0; j < 4; ++j) {
                    aK[i][j] = __builtin_amdgcn_mfma_f32_16x16x32_bf16(a[i], bK[j], aK[i][j], 0, 0, 0);
                    aV[i][j] = __builtin_amdgcn_mfma_f32_16x16x32_bf16(a[i], bV[j], aV[i][j], 0, 0, 0);
                }
        }
    }

    const int h = n0 >> 7;
    const int b_ = m0 >> 12, tbase = m0 & 4095;

#pragma unroll
    for (int i = 0; i < 4; ++i) {
#pragma unroll
        for (int j = 0; j < 4; ++j) {
            int col = n0 + wn + j * 16 + c15;
            float bkv = bk[col];
            int d = col & 127;
#pragma unroll
            for (int r = 0; r < 4; ++r) {
                int row = m0 + wm + i * 16 + g * 4 + r;
                int t = row & 4095;
                Kout[(((size_t)(b_ * 8 + h) << 12) + t) * 128 + d] = f2bf(aK[i][j][r] + bkv);
            }
        }
    }

    __syncthreads();
    US* T = lds;                                // [d 128][kv 128], stride 136
#pragma unroll
    for (int i = 0; i < 4; ++i) {
#pragma unroll
        for (int j = 0; j < 4; ++j) {
            int dcol = wn + j * 16 + c15;
            float bvv = bv[n0 + dcol];
#pragma unroll
            for (int r = 0; r < 4; ++r) {
                int kvrow = wm + i * 16 + g * 4 + r;
                T[dcol * 136 + kvrow] = f2bf(aV[i][j][r] + bvv);
            }
        }
    }
    __syncthreads();
    {
        int d = tid >> 1, half = (tid & 1) * 64;
        US* vrow = VTout + ((size_t)(b_ * 8 + h) * 128 + d) * 4096 + tbase + half;
        const US* tr = &T[d * 136 + half];
#pragma unroll
        for (int s = 0; s < 8; ++s)
            *(us8*)(vrow + s * 8) = *(const us8*)(tr + s * 8);
    }
}

// ---------------- flash attention: 64 q-rows/wave, sp=8, bitmask ----------------
// grid 512 = 2 qt (256 q) x 32 bh x 8 sp; id = qt*256 + bh*8 + sp so the 2
// qt-siblings (sharing K/V) are congruent mod 8 -> same XCD L2.
// Per wave: 64 q rows; K/V LDS fragments amortize over 2x more q than before.
__global__ __launch_bounds__(256, 2)
void flash(const US* __restrict__ Qh, const US* __restrict__ Kh,
           const US* __restrict__ VTh, const unsigned long long* __restrict__ MBits,
           US* __restrict__ Opart, float* __restrict__ Lpart) {
    __shared__ US Ks[64 * 128];        // [kv][d] 16KB, swz (r&15)
    __shared__ US Vs[128 * 64];        // [d][kv] 16KB, swz (r&7)
    __shared__ US Ps[4][64 * 64];      // per-wave P [q64][kv64] 32KB, chunk swz (q&7)
    const int tid = threadIdx.x, wv = tid >> 6, ln = tid & 63;
    const int g = ln >> 4, c15 = ln & 15;
    const int bid = blockIdx.x;
    const int qt = bid >> 8;
    const int rest = bid & 255;
    const int bh = rest >> 3, sp = rest & 7;
    const int qbase = qt * 256;
    const int b_ = bh >> 3;
    const int t0 = sp * 8;                       // tiles of 64 kv, nt = 8
    const int wq = wv * 64;

    // Q fragments (B-operand) straight from global: 4 x 16 q-rows per wave
    bf16x8 qa[4][4];
#pragma unroll
    for (int ib = 0; ib < 4; ++ib) {
        const US* qrow = Qh + ((size_t)bh * 512 + qbase + wq + ib * 16 + c15) * 128;
#pragma unroll
        for (int ks = 0; ks < 4; ++ks)
            qa[ib][ks] = ldv8(qrow + ks * 32 + g * 8);
    }

    f32x4 o[8][4];
    const f32x4 z = {0.f, 0.f, 0.f, 0.f};
#pragma unroll
    for (int d = 0; d < 8; ++d)
#pragma unroll
        for (int ib = 0; ib < 4; ++ib) o[d][ib] = z;
    float l4[4] = {0.f, 0.f, 0.f, 0.f};

    const unsigned long long* Mrow[4];
    Mrow[0] = MBits + (size_t)(b_ * 512 + qbase + wq + c15) * 64;
#pragma unroll
    for (int ib = 1; ib < 4; ++ib) Mrow[ib] = Mrow[0] + (size_t)ib * 16 * 64;
    const US* Kbase = Kh + ((size_t)bh * 4096 + (size_t)t0 * 64) * 128;
    const US* Vbase = VTh + (size_t)bh * 128 * 4096;
    US* Pw = &Ps[wv][0];

    for (int t = 0; t < 8; ++t) {
        int kv0 = (t0 + t) * 64;
        __syncthreads();
        const US* Kb = Kbase + (size_t)t * 64 * 128;
#pragma unroll
        for (int q = 0; q < 4; ++q) {               // K tile
            int eb = (q * 256 + wv * 64) * 8;
            int r = (eb >> 7) + (ln >> 4);
            int sw = (ln & 15) ^ (r & 15);
            gl_lds16(Kb + (size_t)r * 128 + sw * 8, &Ks[eb]);
        }
#pragma unroll
        for (int q = 0; q < 4; ++q) {               // V^T tile
            int eb = (q * 256 + wv * 64) * 8;
            int r = (eb >> 6) + (ln >> 3);
            int sw = (ln & 7) ^ (r & 7);
            gl_lds16(Vbase + (size_t)r * 4096 + kv0 + sw * 8, &Vs[eb]);
        }
        unsigned long long m64[4];
#pragma unroll
        for (int ib = 0; ib < 4; ++ib) m64[ib] = Mrow[ib][t0 + t];
        __syncthreads();

        // S^T per kb: 16 kv x 64 q, then exp/mask -> P LDS
#pragma unroll
        for (int kb = 0; kb < 4; ++kb) {
            f32x4 s[4];
#pragma unroll
            for (int ib = 0; ib < 4; ++ib) s[ib] = z;
#pragma unroll
            for (int ks = 0; ks < 4; ++ks) {
                bf16x8 kf = ldv8(&Ks[(kb * 16 + c15) * 128 + (((ks * 4 + g) ^ c15) * 8)]);
#pragma unroll
                for (int ib = 0; ib < 4; ++ib)
                    s[ib] = __builtin_amdgcn_mfma_f32_16x16x32_bf16(kf, qa[ib][ks], s[ib], 0, 0, 0);
            }
            int cw = kb * 4 + g;
#pragma unroll
            for (int ib = 0; ib < 4; ++ib) {
                unsigned mq = (unsigned)(m64[ib] >> (kb * 16 + g * 4)) & 15u;
                float p0 = (mq & 1u) ? __expf(s[ib][0]) : 0.f;
                float p1 = (mq & 2u) ? __expf(s[ib][1]) : 0.f;
                float p2 = (mq & 4u) ? __expf(s[ib][2]) : 0.f;
                float p3 = (mq & 8u) ? __expf(s[ib][3]) : 0.f;
                l4[ib] += (p0 + p1) + (p2 + p3);
                int q = ib * 16 + c15;
                US* wp = Pw + q * 64 + (((cw >> 1) ^ (q & 7)) * 8) + (cw & 1) * 4;
                us4 pv = { f2bf(p0), f2bf(p1), f2bf(p2), f2bf(p3) };
                *(us4*)wp = pv;
            }
        }

        // O^T += V^T P^T
#pragma unroll
        for (int ks = 0; ks < 2; ++ks) {
            bf16x8 pf[4];
#pragma unroll
            for (int ib = 0; ib < 4; ++ib) {
                int q = ib * 16 + c15;
                pf[ib] = ldv8(&Pw[q * 64 + (((ks * 4 + g) ^ (q & 7)) * 8)]);
            }
#pragma unroll
            for (int d = 0; d < 8; ++d) {
                bf16x8 vf = ldv8(&Vs[(d * 16 + c15) * 64 + (((ks * 4 + g) ^ (c15 & 7)) * 8)]);
#pragma unroll
                for (int ib = 0; ib < 4; ++ib)
                    o[d][ib] = __builtin_amdgcn_mfma_f32_16x16x32_bf16(vf, pf[ib], o[d][ib], 0, 0, 0);
            }
        }
    }

    // l: reduce over the 4 g-lanes sharing c15
    float lf[4];
#pragma unroll
    for (int ib = 0; ib < 4; ++ib) {
        float l = l4[ib];
        l += __shfl_xor(l, 16); l += __shfl_xor(l, 32);
        lf[ib] = l;
    }
    if (ln < 16) {
        size_t lb = ((size_t)sp * 32 + bh) * 512 + qbase + wq + c15;
#pragma unroll
        for (int ib = 0; ib < 4; ++ib) Lpart[lb + ib * 16] = lf[ib];
    }
    // Opart [sp][bh][d=128][q=512], un-normalized bf16 partials
    US* Ob = Opart + (((size_t)sp * 32 + bh) * 128 + g * 4) * 512 + qbase + wq + c15;
#pragma unroll
    for (int d = 0; d < 8; ++d)
#pragma unroll
        for (int r = 0; r < 4; ++r)
#pragma unroll
            for (int ib = 0; ib < 4; ++ib)
                Ob[(size_t)(d * 16 + r) * 512 + ib * 16] = f2bf(o[d][ib][r]);
}

// ---------------- combine: sum 8 bf16 splits, normalize, transpose -> AO bf16 ----------------
__global__ void combine(const US* __restrict__ Opart, const float* __restrict__ Lpart,
                        US* __restrict__ AO) {
    __shared__ float linv[128];
    __shared__ float T[128 * 33];
    const int qt = blockIdx.x, bh = blockIdx.y;
    const int b_ = bh >> 3, h = bh & 7;
    const int tid = threadIdx.x;
    const size_t spstride = (size_t)32 * 128 * 512;

    if (tid < 128) {
        float s = 0.f;
#pragma unroll
        for (int sp = 0; sp < 8; ++sp)
            s += Lpart[((size_t)sp * 32 + bh) * 512 + qt * 128 + tid];
        linv[tid] = (s > 0.f) ? 1.f / s : 0.f;
    }
    __syncthreads();

    for (int ds0 = 0; ds0 < 128; ds0 += 32) {
        if (ds0) __syncthreads();
        {
            int d = ds0 + (tid >> 3);
            int q0 = (tid & 7) * 16;
            const US* base = Opart + ((size_t)bh * 128 + d) * 512 + qt * 128 + q0;
            float acc[16];
#pragma unroll
            for (int i = 0; i < 16; ++i) acc[i] = 0.f;
#pragma unroll
            for (int sp = 0; sp < 8; ++sp) {
                us8 a = *(const us8*)(base + sp * spstride);
                us8 b = *(const us8*)(base + sp * spstride + 8);
#pragma unroll
                for (int i = 0; i < 8; ++i) {
                    acc[i] += bf2f(a[i]);
                    acc[8 + i] += bf2f(b[i]);
                }
            }
            int dd = d - ds0;
#pragma unroll
            for (int i = 0; i < 16; ++i)
                T[(q0 + i) * 33 + dd] = acc[i] * linv[q0 + i];
        }
        __syncthreads();
#pragma unroll
        for (int it = 0; it < 4; ++it) {
            int idx = tid + it * 256;
            int q = idx >> 3, c = idx & 7;
            const float* tr = &T[q * 33 + c * 4];
            us4 ov = { f2bf(tr[0]), f2bf(tr[1]), f2bf(tr[2]), f2bf(tr[3]) };
            *(us4*)(AO + ((size_t)(b_ * 512 + qt * 128 + q)) * 1024 + h * 128 + ds0 + c * 4) = ov;
        }
    }
}

// ---------------- launch ----------------
extern "C" void kernel_launch(void* const* d_in, const int* in_sizes, int n_in,
                              void* d_out, int out_size, void* d_ws, size_t ws_size,
                              hipStream_t stream) {
    (void)in_sizes; (void)n_in; (void)out_size; (void)ws_size;
    const float* Xq  = (const float*)d_in[0];
    const float* Xkv = (const float*)d_in[1];
    const int*   Mi  = (const int*)d_in[2];
    const float* Wq  = (const float*)d_in[3];
    const float* bq  = (const float*)d_in[4];
    const float* Wk  = (const float*)d_in[5];
    const float* bk  = (const float*)d_in[6];
    const float* Wv  = (const float*)d_in[7];
    const float* bv  = (const float*)d_in[8];
    const float* Wo  = (const float*)d_in[9];
    const float* bo  = (const float*)d_in[10];
    float* out = (float*)d_out;

    // ws layout (aliasing is stream-order safe):
    char* p = (char*)d_ws;
    US* WT   = (US*)p; p += (size_t)4 * 1024 * 1024 * 2;     // 8.4 MB, live to end
    US* AO   = (US*)p; p += (size_t)2048 * 1024 * 2;         // 4.2 MB
    US* XqB  = (US*)p; p += (size_t)2048 * 1024 * 2;         // 4.2 MB, dead after Q-proj
    US* Qh   = (US*)p; p += (size_t)2048 * 1024 * 2;         // 4.2 MB
    US* Kh   = (US*)p; p += (size_t)16384 * 1024 * 2;        // 33.5 MB
    US* VTh  = (US*)p; p += (size_t)16384 * 1024 * 2;        // 33.5 MB
    US* XkvB = (US*)p; p += (size_t)16384 * 1024 * 2;        // 33.5 MB, dead after gemm_kv
    unsigned long long* MBits = (unsigned long long*)p; p += (size_t)131072 * 8;  // 1 MB
    US* Opart    = XkvB;           // 33.5 MB bf16 partials (sp=8) inside XkvB
    float* Lpart = (float*)XqB;    // 524 KB; XqB dead after Q-proj

    prep<<<4096, 256, 0, stream>>>(Xq, Xkv, Mi, MBits, XqB, XkvB, Wq, Wk, Wv, Wo, WT);

    // Q projection: fold softmax scale 1/sqrt(128) into Q
    gemm_bt<0, 64><<<dim3(32, 8), 256, 0, stream>>>(XqB, WT, bq, Qh, 9, 0.08838834764831843f);
    gemm_kv<<<dim3(128, 8), 256, 0, stream>>>(XkvB, WT + 1048576, WT + 2097152,
                                              bk, bv, Kh, VTh);
    flash<<<512, 256, 0, stream>>>(Qh, Kh, VTh, MBits, Opart, Lpart);
    combine<<<dim3(4, 32), 256, 0, stream>>>(Opart, Lpart, AO);
    gemm_bt<1, 64><<<dim3(32, 8), 256, 0, stream>>>(AO, WT + 3145728, bo, out, 0, 1.0f);
}

// Round 9
// 423.901 us; speedup vs baseline: 1.0293x; 1.0293x over previous
//
#include <hip/hip_runtime.h>
#include <cstdint>
#include <cstddef>

typedef unsigned short US;
typedef __bf16 bf16_t;
typedef bf16_t bf16x8 __attribute__((ext_vector_type(8)));
typedef float  f32x4  __attribute__((ext_vector_type(4)));
typedef US     us8    __attribute__((ext_vector_type(8)));
typedef US     us4    __attribute__((ext_vector_type(4)));

#define AS1 __attribute__((address_space(1)))
#define AS3 __attribute__((address_space(3)))

__device__ __forceinline__ void gl_lds16(const void* g, void* l) {
    __builtin_amdgcn_global_load_lds((AS1 unsigned int*)(size_t)g,
                                     (AS3 unsigned int*)l, 16, 0, 0);
}

__device__ __forceinline__ US f2bf(float f) {
    unsigned u = __builtin_bit_cast(unsigned, f);
    u += 0x7FFFu + ((u >> 16) & 1u);   // RNE (inputs finite)
    return (US)(u >> 16);
}

__device__ __forceinline__ float bf2f(US u) {
    return __builtin_bit_cast(float, (unsigned)u << 16);
}

__device__ __forceinline__ bf16x8 ldv8(const US* p) {
    return __builtin_bit_cast(bf16x8, *(const us8*)p);
}

// ---------------- prep: X converts + mask bits (tile-major) + weight transposes ----------
// 4096 fat blocks; all roles HBM-streaming (L2-safe to fuse; never fuse with GEMMs).
// MBits layout [b][kv_tile 64][q 512]: flash reads per-tile mask rows coalesced.
__global__ void prep(const float* __restrict__ Xq, const float* __restrict__ Xkv,
                     const int* __restrict__ Mi, unsigned long long* __restrict__ MBits,
                     US* __restrict__ XqB, US* __restrict__ XkvB,
                     const float* __restrict__ Wq, const float* __restrict__ Wk,
                     const float* __restrict__ Wv, const float* __restrict__ Wo,
                     US* __restrict__ WTbase) {
    __shared__ float t[32][33];
    const int b = blockIdx.x, tid = threadIdx.x;

    for (int u = b; u < 18432; u += 4096) {
        if (u < 2048) {
            int i = u * 256 + tid;
            float4 f = ((const float4*)Xq)[i];
            us4 o = { f2bf(f.x), f2bf(f.y), f2bf(f.z), f2bf(f.w) };
            ((us4*)XqB)[i] = o;
        } else {
            int i = (u - 2048) * 256 + tid;
            float4 f = ((const float4*)Xkv)[i];
            us4 o = { f2bf(f.x), f2bf(f.y), f2bf(f.z), f2bf(f.w) };
            ((us4*)XkvB)[i] = o;
        }
    }

    for (int u = b; u < 32768; u += 4096) {
        int i = u * 256 + tid;                 // wave = 64 consecutive kv of one (b,q)
        int m = Mi[i];
        unsigned long long bits = __ballot(m != 0);
        if ((tid & 63) == 0) {
            int b_ = i >> 21, q = (i >> 12) & 511, kt = (i & 4095) >> 6;
            MBits[((size_t)(b_ * 64 + kt)) * 512 + q] = bits;
        }
    }

    {
        int z = b >> 10, rr = b & 1023;
        int bx = rr & 31, by = rr >> 5;
        const float* W = (z == 0) ? Wq : (z == 1) ? Wk : (z == 2) ? Wv : Wo;
        US* WT = WTbase + (size_t)z * 1024 * 1024;
        int tx = tid & 31, ty = tid >> 5;
        int x = bx * 32 + tx;
#pragma unroll
        for (int r = 0; r < 4; ++r)
            t[ty + r * 8][tx] = W[(size_t)(by * 32 + ty + r * 8) * 1024 + x];
        __syncthreads();
        int nx = by * 32 + tx;
#pragma unroll
        for (int r = 0; r < 4; ++r)
            WT[(size_t)(bx * 32 + ty + r * 8) * 1024 + nx] = f2bf(t[tx][ty + r * 8]);
    }
}

// ---------------- GEMM: C[M,1024] = A[M,1024]bf16 @ Bt[1024,1024]^T + bias ----------------
template <int MODE, int BM>
__global__ __launch_bounds__(256, 2)
void gemm_bt(const US* __restrict__ A, const US* __restrict__ Bt,
             const float* __restrict__ bias, void* __restrict__ out,
             int tlog2, float scale) {
    constexpr int K = 1024, N = 1024, BK = 64;
    constexpr int MI = BM / 32;
    __shared__ US As[BM * BK];
    __shared__ US Bs[128 * BK];
    const int tid = threadIdx.x;
    const int wv = tid >> 6, ln = tid & 63;
    const int g = ln >> 4, c15 = ln & 15;
    const int m0 = blockIdx.x * BM, n0 = blockIdx.y * 128;
    const int wm = (wv & 1) * (BM / 2), wn = (wv >> 1) * 64;

    f32x4 acc[MI][4];
    const f32x4 z = {0.f, 0.f, 0.f, 0.f};
#pragma unroll
    for (int i = 0; i < MI; ++i)
#pragma unroll
        for (int j = 0; j < 4; ++j) acc[i][j] = z;

    const US* Ab = A + (size_t)m0 * K;
    const US* Bb = Bt + (size_t)n0 * K;

    for (int k0 = 0; k0 < K; k0 += BK) {
        __syncthreads();
#pragma unroll
        for (int q = 0; q < BM / 32; ++q) {
            int eb = (q * 256 + wv * 64) * 8;
            int r = (eb >> 6) + (ln >> 3);
            int sw = (ln & 7) ^ (r & 7);
            gl_lds16(Ab + (size_t)r * K + k0 + sw * 8, &As[eb]);
        }
#pragma unroll
        for (int q = 0; q < 4; ++q) {
            int eb = (q * 256 + wv * 64) * 8;
            int r = (eb >> 6) + (ln >> 3);
            int sw = (ln & 7) ^ (r & 7);
            gl_lds16(Bb + (size_t)r * K + k0 + sw * 8, &Bs[eb]);
        }
        __syncthreads();
#pragma unroll
        for (int ks = 0; ks < 2; ++ks) {
            bf16x8 a[MI], b[4];
#pragma unroll
            for (int i = 0; i < MI; ++i) {
                int p = (ks * 4 + g) ^ (c15 & 7);
                a[i] = ldv8(&As[(wm + i * 16 + c15) * BK + p * 8]);
            }
#pragma unroll
            for (int j = 0; j < 4; ++j) {
                int p = (ks * 4 + g) ^ (c15 & 7);
                b[j] = ldv8(&Bs[(wn + j * 16 + c15) * BK + p * 8]);
            }
#pragma unroll
            for (int i = 0; i < MI; ++i)
#pragma unroll
                for (int j = 0; j < 4; ++j)
                    acc[i][j] = __builtin_amdgcn_mfma_f32_16x16x32_bf16(a[i], b[j], acc[i][j], 0, 0, 0);
        }
    }

#pragma unroll
    for (int i = 0; i < MI; ++i) {
#pragma unroll
        for (int j = 0; j < 4; ++j) {
            int col = n0 + wn + j * 16 + c15;
            float bvv = bias[col];
#pragma unroll
            for (int r = 0; r < 4; ++r) {
                int row = m0 + wm + i * 16 + g * 4 + r;
                float v = (acc[i][j][r] + bvv) * scale;
                if (MODE == 0) {
                    int b_ = row >> tlog2;
                    int t = row & ((1 << tlog2) - 1);
                    int h = col >> 7, d = col & 127;
                    ((US*)out)[(((size_t)(b_ * 8 + h) << tlog2) + t) * 128 + d] = f2bf(v);
                } else {
                    ((float*)out)[(size_t)row * N + col] = v;
                }
            }
        }
    }
}

// ---------------- fused K+V projection GEMM; V written pre-transposed ----------------
__global__ __launch_bounds__(256, 2)
void gemm_kv(const US* __restrict__ A, const US* __restrict__ BtK,
             const US* __restrict__ BtV, const float* __restrict__ bk,
             const float* __restrict__ bv, US* __restrict__ Kout,
             US* __restrict__ VTout) {
    constexpr int K = 1024, BK = 64;
    __shared__ US lds[3 * 128 * BK];
    US* As  = lds;
    US* BsK = lds + 128 * BK;
    US* BsV = lds + 2 * 128 * BK;
    const int tid = threadIdx.x;
    const int wv = tid >> 6, ln = tid & 63;
    const int g = ln >> 4, c15 = ln & 15;
    const int m0 = blockIdx.x * 128, n0 = blockIdx.y * 128;
    const int wm = (wv & 1) * 64, wn = (wv >> 1) * 64;

    f32x4 aK[4][4], aV[4][4];
    const f32x4 z = {0.f, 0.f, 0.f, 0.f};
#pragma unroll
    for (int i = 0; i < 4; ++i)
#pragma unroll
        for (int j = 0; j < 4; ++j) { aK[i][j] = z; aV[i][j] = z; }

    const US* Ab  = A   + (size_t)m0 * K;
    const US* BbK = BtK + (size_t)n0 * K;
    const US* BbV = BtV + (size_t)n0 * K;

    for (int k0 = 0; k0 < K; k0 += BK) {
        __syncthreads();
#pragma unroll
        for (int q = 0; q < 4; ++q) {
            int eb = (q * 256 + wv * 64) * 8;
            int r = (eb >> 6) + (ln >> 3);
            int sw = (ln & 7) ^ (r & 7);
            gl_lds16(Ab  + (size_t)r * K + k0 + sw * 8, &As[eb]);
            gl_lds16(BbK + (size_t)r * K + k0 + sw * 8, &BsK[eb]);
            gl_lds16(BbV + (size_t)r * K + k0 + sw * 8, &BsV[eb]);
        }
        __syncthreads();
#pragma unroll
        for (int ks = 0; ks < 2; ++ks) {
            bf16x8 a[4], bK[4], bV[4];
#pragma unroll
            for (int i = 0; i < 4; ++i) {
                int p = (ks * 4 + g) ^ (c15 & 7);
                a[i] = ldv8(&As[(wm + i * 16 + c15) * BK + p * 8]);
            }
#pragma unroll
            for (int j = 0; j < 4; ++j) {
                int p = (ks * 4 + g) ^ (c15 & 7);
                bK[j] = ldv8(&BsK[(wn + j * 16 + c15) * BK + p * 8]);
                bV[j] = ldv8(&BsV[(wn + j * 16 + c15) * BK + p * 8]);
            }
#pragma unroll
            for (int i = 0; i < 4; ++i)
#pragma unroll
                for (int j = 0; j < 4; ++j) {
                    aK[i][j] = __builtin_amdgcn_mfma_f32_16x16x32_bf16(a[i], bK[j], aK[i][j], 0, 0, 0);
                    aV[i][j] = __builtin_amdgcn_mfma_f32_16x16x32_bf16(a[i], bV[j], aV[i][j], 0, 0, 0);
                }
        }
    }

    const int h = n0 >> 7;
    const int b_ = m0 >> 12, tbase = m0 & 4095;

#pragma unroll
    for (int i = 0; i < 4; ++i) {
#pragma unroll
        for (int j = 0; j < 4; ++j) {
            int col = n0 + wn + j * 16 + c15;
            float bkv = bk[col];
            int d = col & 127;
#pragma unroll
            for (int r = 0; r < 4; ++r) {
                int row = m0 + wm + i * 16 + g * 4 + r;
                int t = row & 4095;
                Kout[(((size_t)(b_ * 8 + h) << 12) + t) * 128 + d] = f2bf(aK[i][j][r] + bkv);
            }
        }
    }

    __syncthreads();
    US* T = lds;                                // [d 128][kv 128], stride 136
#pragma unroll
    for (int i = 0; i < 4; ++i) {
#pragma unroll
        for (int j = 0; j < 4; ++j) {
            int dcol = wn + j * 16 + c15;
            float bvv = bv[n0 + dcol];
#pragma unroll
            for (int r = 0; r < 4; ++r) {
                int kvrow = wm + i * 16 + g * 4 + r;
                T[dcol * 136 + kvrow] = f2bf(aV[i][j][r] + bvv);
            }
        }
    }
    __syncthreads();
    {
        int d = tid >> 1, half = (tid & 1) * 64;
        US* vrow = VTout + ((size_t)(b_ * 8 + h) * 128 + d) * 4096 + tbase + half;
        const US* tr = &T[d * 136 + half];
#pragma unroll
        for (int s = 0; s < 8; ++s)
            *(us8*)(vrow + s * 8) = *(const us8*)(tr + s * 8);
    }
}

// ---------------- flash: 64 q/wave, sp=8, bitmask(tile-major), q-major Opart ----------
// grid 512 = 2 qt x 32 bh x 8 sp; id = qt*256 + bh*8 + sp (qt siblings same XCD).
// Epilogue transposes O^T regs -> q-major via per-wave LDS, stores full-line us8.
__global__ __launch_bounds__(256, 2)
void flash(const US* __restrict__ Qh, const US* __restrict__ Kh,
           const US* __restrict__ VTh, const unsigned long long* __restrict__ MBits,
           US* __restrict__ Opart, float* __restrict__ Lpart) {
    __shared__ US Ks[64 * 128];        // [kv][d] 16KB, swz (r&15)
    __shared__ US Vs[128 * 64];        // [d][kv] 16KB, swz (r&7)
    __shared__ US Ps[4][64 * 64];      // per-wave P [q64][kv64] 32KB, chunk swz (q&7)
    const int tid = threadIdx.x, wv = tid >> 6, ln = tid & 63;
    const int g = ln >> 4, c15 = ln & 15;
    const int bid = blockIdx.x;
    const int qt = bid >> 8;
    const int rest = bid & 255;
    const int bh = rest >> 3, sp = rest & 7;
    const int qbase = qt * 256;
    const int b_ = bh >> 3;
    const int t0 = sp * 8;                       // 8 tiles of 64 kv per split
    const int wq = wv * 64;

    bf16x8 qa[4][4];
#pragma unroll
    for (int ib = 0; ib < 4; ++ib) {
        const US* qrow = Qh + ((size_t)bh * 512 + qbase + wq + ib * 16 + c15) * 128;
#pragma unroll
        for (int ks = 0; ks < 4; ++ks)
            qa[ib][ks] = ldv8(qrow + ks * 32 + g * 8);
    }

    f32x4 o[8][4];
    const f32x4 z = {0.f, 0.f, 0.f, 0.f};
#pragma unroll
    for (int d = 0; d < 8; ++d)
#pragma unroll
        for (int ib = 0; ib < 4; ++ib) o[d][ib] = z;
    float l4[4] = {0.f, 0.f, 0.f, 0.f};

    // tile-major mask: [b][kt][q] -> coalesced 8B loads, 16 lanes contiguous
    const unsigned long long* Mb = MBits + ((size_t)(b_ * 64 + t0)) * 512
                                 + qbase + wq + c15;
    const US* Kbase = Kh + ((size_t)bh * 4096 + (size_t)t0 * 64) * 128;
    const US* Vbase = VTh + (size_t)bh * 128 * 4096;
    US* Pw = &Ps[wv][0];

    for (int t = 0; t < 8; ++t) {
        int kv0 = (t0 + t) * 64;
        __syncthreads();
        const US* Kb = Kbase + (size_t)t * 64 * 128;
#pragma unroll
        for (int q = 0; q < 4; ++q) {               // K tile
            int eb = (q * 256 + wv * 64) * 8;
            int r = (eb >> 7) + (ln >> 4);
            int sw = (ln & 15) ^ (r & 15);
            gl_lds16(Kb + (size_t)r * 128 + sw * 8, &Ks[eb]);
        }
#pragma unroll
        for (int q = 0; q < 4; ++q) {               // V^T tile
            int eb = (q * 256 + wv * 64) * 8;
            int r = (eb >> 6) + (ln >> 3);
            int sw = (ln & 7) ^ (r & 7);
            gl_lds16(Vbase + (size_t)r * 4096 + kv0 + sw * 8, &Vs[eb]);
        }
        unsigned long long m64[4];
#pragma unroll
        for (int ib = 0; ib < 4; ++ib) m64[ib] = Mb[(size_t)t * 512 + ib * 16];
        __syncthreads();

        // S^T per kb: 16 kv x 64 q, then exp/mask -> P LDS
#pragma unroll
        for (int kb = 0; kb < 4; ++kb) {
            f32x4 s[4];
#pragma unroll
            for (int ib = 0; ib < 4; ++ib) s[ib] = z;
#pragma unroll
            for (int ks = 0; ks < 4; ++ks) {
                bf16x8 kf = ldv8(&Ks[(kb * 16 + c15) * 128 + (((ks * 4 + g) ^ c15) * 8)]);
#pragma unroll
                for (int ib = 0; ib < 4; ++ib)
                    s[ib] = __builtin_amdgcn_mfma_f32_16x16x32_bf16(kf, qa[ib][ks], s[ib], 0, 0, 0);
            }
            int cw = kb * 4 + g;
#pragma unroll
            for (int ib = 0; ib < 4; ++ib) {
                unsigned mq = (unsigned)(m64[ib] >> (kb * 16 + g * 4)) & 15u;
                float p0 = (mq & 1u) ? __expf(s[ib][0]) : 0.f;
                float p1 = (mq & 2u) ? __expf(s[ib][1]) : 0.f;
                float p2 = (mq & 4u) ? __expf(s[ib][2]) : 0.f;
                float p3 = (mq & 8u) ? __expf(s[ib][3]) : 0.f;
                l4[ib] += (p0 + p1) + (p2 + p3);
                int q = ib * 16 + c15;
                US* wp = Pw + q * 64 + (((cw >> 1) ^ (q & 7)) * 8) + (cw & 1) * 4;
                us4 pv = { f2bf(p0), f2bf(p1), f2bf(p2), f2bf(p3) };
                *(us4*)wp = pv;
            }
        }

        // O^T += V^T P^T
#pragma unroll
        for (int ks = 0; ks < 2; ++ks) {
            bf16x8 pf[4];
#pragma unroll
            for (int ib = 0; ib < 4; ++ib) {
                int q = ib * 16 + c15;
                pf[ib] = ldv8(&Pw[q * 64 + (((ks * 4 + g) ^ (q & 7)) * 8)]);
            }
#pragma unroll
            for (int d = 0; d < 8; ++d) {
                bf16x8 vf = ldv8(&Vs[(d * 16 + c15) * 64 + (((ks * 4 + g) ^ (c15 & 7)) * 8)]);
#pragma unroll
                for (int ib = 0; ib < 4; ++ib)
                    o[d][ib] = __builtin_amdgcn_mfma_f32_16x16x32_bf16(vf, pf[ib], o[d][ib], 0, 0, 0);
            }
        }
    }

    // l: reduce over the 4 g-lanes sharing c15
    float lf[4];
#pragma unroll
    for (int ib = 0; ib < 4; ++ib) {
        float l = l4[ib];
        l += __shfl_xor(l, 16); l += __shfl_xor(l, 32);
        lf[ib] = l;
    }
    if (ln < 16) {
        size_t lb = ((size_t)sp * 32 + bh) * 512 + qbase + wq + c15;
#pragma unroll
        for (int ib = 0; ib < 4; ++ib) Lpart[lb + ib * 16] = lf[ib];
    }

    // epilogue: O^T regs -> q-major Opart [sp][bh][q][d] via per-wave LDS transpose.
    // Writes us4 (2-way banks, free); reads us8 logical-chunk oct; stores 128B/row.
    __syncthreads();                            // Ps main-loop reads done (all waves)
    size_t obase = (((size_t)sp * 32 + bh) * 512 + qbase + wq) * 128;
#pragma unroll
    for (int half = 0; half < 2; ++half) {
#pragma unroll
        for (int d = 0; d < 4; ++d) {
            int dg = half * 4 + d;
            int c = d * 2 + (g >> 1), sub = g & 1;
#pragma unroll
            for (int ib = 0; ib < 4; ++ib) {
                int q = ib * 16 + c15;
                us4 pv = { f2bf(o[dg][ib][0]), f2bf(o[dg][ib][1]),
                           f2bf(o[dg][ib][2]), f2bf(o[dg][ib][3]) };
                *(us4*)&Pw[q * 64 + ((c ^ (q & 7)) * 8) + sub * 4] = pv;
            }
        }
        // per-wave LDS: same-wave write->read ordering handled by lgkmcnt
#pragma unroll
        for (int p = 0; p < 8; ++p) {
            int q = p * 8 + (ln >> 3);
            int oct = ln & 7;
            us8 v = *(const us8*)&Pw[q * 64 + ((oct ^ (q & 7)) * 8)];
            *(us8*)(Opart + obase + (size_t)q * 128 + half * 64 + oct * 8) = v;
        }
    }
}

// ---------------- combine: q-major streaming sum of 8 splits -> AO bf16 ----------------
__global__ void combine(const US* __restrict__ Opart, const float* __restrict__ Lpart,
                        US* __restrict__ AO) {
    __shared__ float linv[128];
    const int qt = blockIdx.x, bh = blockIdx.y;
    const int b_ = bh >> 3, h = bh & 7;
    const int tid = threadIdx.x;
    const size_t spO = (size_t)32 * 512 * 128;
    const size_t spL = (size_t)32 * 512;

    if (tid < 128) {
        float s = 0.f;
#pragma unroll
        for (int sp = 0; sp < 8; ++sp)
            s += Lpart[sp * spL + (size_t)bh * 512 + qt * 128 + tid];
        linv[tid] = (s > 0.f) ? 1.f / s : 0.f;
    }
    __syncthreads();

#pragma unroll
    for (int p = 0; p < 8; ++p) {
        int ql = p * 16 + (tid >> 4);
        int d = (tid & 15) * 8;
        const US* base = Opart + ((size_t)bh * 512 + qt * 128 + ql) * 128 + d;
        float acc[8];
#pragma unroll
        for (int i = 0; i < 8; ++i) acc[i] = 0.f;
#pragma unroll
        for (int sp = 0; sp < 8; ++sp) {
            us8 v = *(const us8*)(base + sp * spO);
#pragma unroll
            for (int i = 0; i < 8; ++i) acc[i] += bf2f(v[i]);
        }
        float iv = linv[ql];
        us8 ov;
#pragma unroll
        for (int i = 0; i < 8; ++i) ov[i] = f2bf(acc[i] * iv);
        *(us8*)(AO + ((size_t)(b_ * 512 + qt * 128 + ql)) * 1024 + h * 128 + d) = ov;
    }
}

// ---------------- launch ----------------
extern "C" void kernel_launch(void* const* d_in, const int* in_sizes, int n_in,
                              void* d_out, int out_size, void* d_ws, size_t ws_size,
                              hipStream_t stream) {
    (void)in_sizes; (void)n_in; (void)out_size; (void)ws_size;
    const float* Xq  = (const float*)d_in[0];
    const float* Xkv = (const float*)d_in[1];
    const int*   Mi  = (const int*)d_in[2];
    const float* Wq  = (const float*)d_in[3];
    const float* bq  = (const float*)d_in[4];
    const float* Wk  = (const float*)d_in[5];
    const float* bk  = (const float*)d_in[6];
    const float* Wv  = (const float*)d_in[7];
    const float* bv  = (const float*)d_in[8];
    const float* Wo  = (const float*)d_in[9];
    const float* bo  = (const float*)d_in[10];
    float* out = (float*)d_out;

    // ws layout (aliasing is stream-order safe):
    char* p = (char*)d_ws;
    US* WT   = (US*)p; p += (size_t)4 * 1024 * 1024 * 2;     // 8.4 MB, live to end
    US* AO   = (US*)p; p += (size_t)2048 * 1024 * 2;         // 4.2 MB
    US* XqB  = (US*)p; p += (size_t)2048 * 1024 * 2;         // 4.2 MB, dead after Q-proj
    US* Qh   = (US*)p; p += (size_t)2048 * 1024 * 2;         // 4.2 MB
    US* Kh   = (US*)p; p += (size_t)16384 * 1024 * 2;        // 33.5 MB
    US* VTh  = (US*)p; p += (size_t)16384 * 1024 * 2;        // 33.5 MB
    US* XkvB = (US*)p; p += (size_t)16384 * 1024 * 2;        // 33.5 MB, dead after gemm_kv
    unsigned long long* MBits = (unsigned long long*)p; p += (size_t)131072 * 8;  // 1 MB
    US* Opart    = XkvB;           // 33.5 MB bf16 partials [8][32][512][128] in XkvB
    float* Lpart = (float*)XqB;    // 524 KB; XqB dead after Q-proj

    prep<<<4096, 256, 0, stream>>>(Xq, Xkv, Mi, MBits, XqB, XkvB, Wq, Wk, Wv, Wo, WT);

    // Q projection: fold softmax scale 1/sqrt(128) into Q
    gemm_bt<0, 64><<<dim3(32, 8), 256, 0, stream>>>(XqB, WT, bq, Qh, 9, 0.08838834764831843f);
    gemm_kv<<<dim3(128, 8), 256, 0, stream>>>(XkvB, WT + 1048576, WT + 2097152,
                                              bk, bv, Kh, VTh);
    flash<<<512, 256, 0, stream>>>(Qh, Kh, VTh, MBits, Opart, Lpart);
    combine<<<dim3(4, 32), 256, 0, stream>>>(Opart, Lpart, AO);
    gemm_bt<1, 64><<<dim3(32, 8), 256, 0, stream>>>(AO, WT + 3145728, bo, out, 0, 1.0f);
}

// Round 10
// 354.119 us; speedup vs baseline: 1.2321x; 1.1971x over previous
//
#include <hip/hip_runtime.h>
#include <cstdint>
#include <cstddef>

typedef unsigned short US;
typedef __bf16 bf16_t;
typedef bf16_t bf16x8 __attribute__((ext_vector_type(8)));
typedef float  f32x4  __attribute__((ext_vector_type(4)));
typedef US     us8    __attribute__((ext_vector_type(8)));
typedef US     us4    __attribute__((ext_vector_type(4)));

#define AS1 __attribute__((address_space(1)))
#define AS3 __attribute__((address_space(3)))

__device__ __forceinline__ void gl_lds16(const void* g, void* l) {
    __builtin_amdgcn_global_load_lds((AS1 unsigned int*)(size_t)g,
                                     (AS3 unsigned int*)l, 16, 0, 0);
}

__device__ __forceinline__ US f2bf(float f) {
    unsigned u = __builtin_bit_cast(unsigned, f);
    u += 0x7FFFu + ((u >> 16) & 1u);   // RNE (inputs finite)
    return (US)(u >> 16);
}

__device__ __forceinline__ float bf2f(US u) {
    return __builtin_bit_cast(float, (unsigned)u << 16);
}

__device__ __forceinline__ bf16x8 ldv8(const US* p) {
    return __builtin_bit_cast(bf16x8, *(const us8*)p);
}

// ---------------- prep: X converts + mask bits (tile-major) + weight transposes ----------
// 4096 fat blocks; all roles HBM-streaming (L2-safe to fuse; never with GEMMs).
// MBits layout [b][kv_tile 64][q 512]: flash mask loads 128B-coalesced.
__global__ void prep(const float* __restrict__ Xq, const float* __restrict__ Xkv,
                     const int* __restrict__ Mi, unsigned long long* __restrict__ MBits,
                     US* __restrict__ XqB, US* __restrict__ XkvB,
                     const float* __restrict__ Wq, const float* __restrict__ Wk,
                     const float* __restrict__ Wv, const float* __restrict__ Wo,
                     US* __restrict__ WTbase) {
    __shared__ float t[32][33];
    const int b = blockIdx.x, tid = threadIdx.x;

    for (int u = b; u < 18432; u += 4096) {
        if (u < 2048) {
            int i = u * 256 + tid;
            float4 f = ((const float4*)Xq)[i];
            us4 o = { f2bf(f.x), f2bf(f.y), f2bf(f.z), f2bf(f.w) };
            ((us4*)XqB)[i] = o;
        } else {
            int i = (u - 2048) * 256 + tid;
            float4 f = ((const float4*)Xkv)[i];
            us4 o = { f2bf(f.x), f2bf(f.y), f2bf(f.z), f2bf(f.w) };
            ((us4*)XkvB)[i] = o;
        }
    }

    for (int u = b; u < 32768; u += 4096) {
        int i = u * 256 + tid;                 // wave = 64 consecutive kv of one (b,q)
        int m = Mi[i];
        unsigned long long bits = __ballot(m != 0);
        if ((tid & 63) == 0) {
            int b_ = i >> 21, q = (i >> 12) & 511, kt = (i & 4095) >> 6;
            MBits[((size_t)(b_ * 64 + kt)) * 512 + q] = bits;
        }
    }

    {
        int z = b >> 10, rr = b & 1023;
        int bx = rr & 31, by = rr >> 5;
        const float* W = (z == 0) ? Wq : (z == 1) ? Wk : (z == 2) ? Wv : Wo;
        US* WT = WTbase + (size_t)z * 1024 * 1024;
        int tx = tid & 31, ty = tid >> 5;
        int x = bx * 32 + tx;
#pragma unroll
        for (int r = 0; r < 4; ++r)
            t[ty + r * 8][tx] = W[(size_t)(by * 32 + ty + r * 8) * 1024 + x];
        __syncthreads();
        int nx = by * 32 + tx;
#pragma unroll
        for (int r = 0; r < 4; ++r)
            WT[(size_t)(bx * 32 + ty + r * 8) * 1024 + nx] = f2bf(t[tx][ty + r * 8]);
    }
}

// ---------------- GEMM: C[M,1024] = A[M,1024]bf16 @ Bt[1024,1024]^T + bias ----------------
template <int MODE, int BM>
__global__ __launch_bounds__(256, 2)
void gemm_bt(const US* __restrict__ A, const US* __restrict__ Bt,
             const float* __restrict__ bias, void* __restrict__ out,
             int tlog2, float scale) {
    constexpr int K = 1024, N = 1024, BK = 64;
    constexpr int MI = BM / 32;
    __shared__ US As[BM * BK];
    __shared__ US Bs[128 * BK];
    const int tid = threadIdx.x;
    const int wv = tid >> 6, ln = tid & 63;
    const int g = ln >> 4, c15 = ln & 15;
    const int m0 = blockIdx.x * BM, n0 = blockIdx.y * 128;
    const int wm = (wv & 1) * (BM / 2), wn = (wv >> 1) * 64;

    f32x4 acc[MI][4];
    const f32x4 z = {0.f, 0.f, 0.f, 0.f};
#pragma unroll
    for (int i = 0; i < MI; ++i)
#pragma unroll
        for (int j = 0; j < 4; ++j) acc[i][j] = z;

    const US* Ab = A + (size_t)m0 * K;
    const US* Bb = Bt + (size_t)n0 * K;

    for (int k0 = 0; k0 < K; k0 += BK) {
        __syncthreads();
#pragma unroll
        for (int q = 0; q < BM / 32; ++q) {
            int eb = (q * 256 + wv * 64) * 8;
            int r = (eb >> 6) + (ln >> 3);
            int sw = (ln & 7) ^ (r & 7);
            gl_lds16(Ab + (size_t)r * K + k0 + sw * 8, &As[eb]);
        }
#pragma unroll
        for (int q = 0; q < 4; ++q) {
            int eb = (q * 256 + wv * 64) * 8;
            int r = (eb >> 6) + (ln >> 3);
            int sw = (ln & 7) ^ (r & 7);
            gl_lds16(Bb + (size_t)r * K + k0 + sw * 8, &Bs[eb]);
        }
        __syncthreads();
#pragma unroll
        for (int ks = 0; ks < 2; ++ks) {
            bf16x8 a[MI], b[4];
#pragma unroll
            for (int i = 0; i < MI; ++i) {
                int p = (ks * 4 + g) ^ (c15 & 7);
                a[i] = ldv8(&As[(wm + i * 16 + c15) * BK + p * 8]);
            }
#pragma unroll
            for (int j = 0; j < 4; ++j) {
                int p = (ks * 4 + g) ^ (c15 & 7);
                b[j] = ldv8(&Bs[(wn + j * 16 + c15) * BK + p * 8]);
            }
#pragma unroll
            for (int i = 0; i < MI; ++i)
#pragma unroll
                for (int j = 0; j < 4; ++j)
                    acc[i][j] = __builtin_amdgcn_mfma_f32_16x16x32_bf16(a[i], b[j], acc[i][j], 0, 0, 0);
        }
    }

#pragma unroll
    for (int i = 0; i < MI; ++i) {
#pragma unroll
        for (int j = 0; j < 4; ++j) {
            int col = n0 + wn + j * 16 + c15;
            float bvv = bias[col];
#pragma unroll
            for (int r = 0; r < 4; ++r) {
                int row = m0 + wm + i * 16 + g * 4 + r;
                float v = (acc[i][j][r] + bvv) * scale;
                if (MODE == 0) {
                    int b_ = row >> tlog2;
                    int t = row & ((1 << tlog2) - 1);
                    int h = col >> 7, d = col & 127;
                    ((US*)out)[(((size_t)(b_ * 8 + h) << tlog2) + t) * 128 + d] = f2bf(v);
                } else {
                    ((float*)out)[(size_t)row * N + col] = v;
                }
            }
        }
    }
}

// ---------------- fused K+V projection GEMM; V written pre-transposed ----------------
__global__ __launch_bounds__(256, 2)
void gemm_kv(const US* __restrict__ A, const US* __restrict__ BtK,
             const US* __restrict__ BtV, const float* __restrict__ bk,
             const float* __restrict__ bv, US* __restrict__ Kout,
             US* __restrict__ VTout) {
    constexpr int K = 1024, BK = 64;
    __shared__ US lds[3 * 128 * BK];
    US* As  = lds;
    US* BsK = lds + 128 * BK;
    US* BsV = lds + 2 * 128 * BK;
    const int tid = threadIdx.x;
    const int wv = tid >> 6, ln = tid & 63;
    const int g = ln >> 4, c15 = ln & 15;
    const int m0 = blockIdx.x * 128, n0 = blockIdx.y * 128;
    const int wm = (wv & 1) * 64, wn = (wv >> 1) * 64;

    f32x4 aK[4][4], aV[4][4];
    const f32x4 z = {0.f, 0.f, 0.f, 0.f};
#pragma unroll
    for (int i = 0; i < 4; ++i)
#pragma unroll
        for (int j = 0; j < 4; ++j) { aK[i][j] = z; aV[i][j] = z; }

    const US* Ab  = A   + (size_t)m0 * K;
    const US* BbK = BtK + (size_t)n0 * K;
    const US* BbV = BtV + (size_t)n0 * K;

    for (int k0 = 0; k0 < K; k0 += BK) {
        __syncthreads();
#pragma unroll
        for (int q = 0; q < 4; ++q) {
            int eb = (q * 256 + wv * 64) * 8;
            int r = (eb >> 6) + (ln >> 3);
            int sw = (ln & 7) ^ (r & 7);
            gl_lds16(Ab  + (size_t)r * K + k0 + sw * 8, &As[eb]);
            gl_lds16(BbK + (size_t)r * K + k0 + sw * 8, &BsK[eb]);
            gl_lds16(BbV + (size_t)r * K + k0 + sw * 8, &BsV[eb]);
        }
        __syncthreads();
#pragma unroll
        for (int ks = 0; ks < 2; ++ks) {
            bf16x8 a[4], bK[4], bV[4];
#pragma unroll
            for (int i = 0; i < 4; ++i) {
                int p = (ks * 4 + g) ^ (c15 & 7);
                a[i] = ldv8(&As[(wm + i * 16 + c15) * BK + p * 8]);
            }
#pragma unroll
            for (int j = 0; j < 4; ++j) {
                int p = (ks * 4 + g) ^ (c15 & 7);
                bK[j] = ldv8(&BsK[(wn + j * 16 + c15) * BK + p * 8]);
                bV[j] = ldv8(&BsV[(wn + j * 16 + c15) * BK + p * 8]);
            }
#pragma unroll
            for (int i = 0; i < 4; ++i)
#pragma unroll
                for (int j = 0; j < 4; ++j) {
                    aK[i][j] = __builtin_amdgcn_mfma_f32_16x16x32_bf16(a[i], bK[j], aK[i][j], 0, 0, 0);
                    aV[i][j] = __builtin_amdgcn_mfma_f32_16x16x32_bf16(a[i], bV[j], aV[i][j], 0, 0, 0);
                }
        }
    }

    const int h = n0 >> 7;
    const int b_ = m0 >> 12, tbase = m0 & 4095;

#pragma unroll
    for (int i = 0; i < 4; ++i) {
#pragma unroll
        for (int j = 0; j < 4; ++j) {
            int col = n0 + wn + j * 16 + c15;
            float bkv = bk[col];
            int d = col & 127;
#pragma unroll
            for (int r = 0; r < 4; ++r) {
                int row = m0 + wm + i * 16 + g * 4 + r;
                int t = row & 4095;
                Kout[(((size_t)(b_ * 8 + h) << 12) + t) * 128 + d] = f2bf(aK[i][j][r] + bkv);
            }
        }
    }

    __syncthreads();
    US* T = lds;                                // [d 128][kv 128], stride 136
#pragma unroll
    for (int i = 0; i < 4; ++i) {
#pragma unroll
        for (int j = 0; j < 4; ++j) {
            int dcol = wn + j * 16 + c15;
            float bvv = bv[n0 + dcol];
#pragma unroll
            for (int r = 0; r < 4; ++r) {
                int kvrow = wm + i * 16 + g * 4 + r;
                T[dcol * 136 + kvrow] = f2bf(aV[i][j][r] + bvv);
            }
        }
    }
    __syncthreads();
    {
        int d = tid >> 1, half = (tid & 1) * 64;
        US* vrow = VTout + ((size_t)(b_ * 8 + h) * 128 + d) * 4096 + tbase + half;
        const US* tr = &T[d * 136 + half];
#pragma unroll
        for (int s = 0; s < 8; ++s)
            *(us8*)(vrow + s * 8) = *(const us8*)(tr + s * 8);
    }
}

// ---------------- flash: 32 q/wave (proven r7 shape), tile-major mask, q-major Opart ----
// grid 768: id = qt*192 + bh*6 + sp (qt siblings same XCD). 4 waves x 32 q.
__global__ __launch_bounds__(256, 3)
void flash(const US* __restrict__ Qh, const US* __restrict__ Kh,
           const US* __restrict__ VTh, const unsigned long long* __restrict__ MBits,
           US* __restrict__ Opart, float* __restrict__ Lpart) {
    __shared__ US Ks[64 * 128];        // [kv][d] 16KB, swz (r&15)
    __shared__ US Vs[128 * 64];        // [d][kv] 16KB, swz (r&7)
    __shared__ US Ps[4][32 * 64];      // per-wave P [q32][kv64] 16KB, chunk swz (q&7)
    const int tid = threadIdx.x, wv = tid >> 6, ln = tid & 63;
    const int g = ln >> 4, c15 = ln & 15;
    const int bid = blockIdx.x;
    const int qt = bid / 192;
    const int rest = bid - qt * 192;
    const int bh = rest / 6, sp = rest - bh * 6;
    const int qbase = qt * 128;
    const int b_ = bh >> 3;
    const int t0 = (sp < 4) ? sp * 11 : 44 + (sp - 4) * 10;   // tiles of 64 kv
    const int nt = (sp < 4) ? 11 : 10;
    const int wq = wv * 32;

    bf16x8 qa[2][4];
#pragma unroll
    for (int ib = 0; ib < 2; ++ib) {
        const US* qrow = Qh + ((size_t)bh * 512 + qbase + wq + ib * 16 + c15) * 128;
#pragma unroll
        for (int ks = 0; ks < 4; ++ks)
            qa[ib][ks] = ldv8(qrow + ks * 32 + g * 8);
    }

    f32x4 o[8][2];
    const f32x4 z = {0.f, 0.f, 0.f, 0.f};
#pragma unroll
    for (int d = 0; d < 8; ++d) { o[d][0] = z; o[d][1] = z; }
    float l2[2] = {0.f, 0.f};

    // tile-major mask [b][kt][q]: 16 c15-lanes load 128B contiguous
    const unsigned long long* Mb = MBits + (size_t)(b_ * 64) * 512 + qbase + wq + c15;
    const US* Kbase = Kh + ((size_t)bh * 4096 + (size_t)t0 * 64) * 128;
    const US* Vbase = VTh + (size_t)bh * 128 * 4096;
    US* Pw = &Ps[wv][0];

    for (int t = 0; t < nt; ++t) {
        int kv0 = (t0 + t) * 64;
        __syncthreads();
        const US* Kb = Kbase + (size_t)t * 64 * 128;
#pragma unroll
        for (int q = 0; q < 4; ++q) {               // K tile
            int eb = (q * 256 + wv * 64) * 8;
            int r = (eb >> 7) + (ln >> 4);
            int sw = (ln & 15) ^ (r & 15);
            gl_lds16(Kb + (size_t)r * 128 + sw * 8, &Ks[eb]);
        }
#pragma unroll
        for (int q = 0; q < 4; ++q) {               // V^T tile
            int eb = (q * 256 + wv * 64) * 8;
            int r = (eb >> 6) + (ln >> 3);
            int sw = (ln & 7) ^ (r & 7);
            gl_lds16(Vbase + (size_t)r * 4096 + kv0 + sw * 8, &Vs[eb]);
        }
        unsigned long long m64[2];
        m64[0] = Mb[(size_t)(t0 + t) * 512];
        m64[1] = Mb[(size_t)(t0 + t) * 512 + 16];
        __syncthreads();

        // S^T per kb: 16 kv x 32 q, then exp/mask -> P LDS
#pragma unroll
        for (int kb = 0; kb < 4; ++kb) {
            f32x4 s0 = z, s1 = z;
#pragma unroll
            for (int ks = 0; ks < 4; ++ks) {
                bf16x8 kf = ldv8(&Ks[(kb * 16 + c15) * 128 + (((ks * 4 + g) ^ c15) * 8)]);
                s0 = __builtin_amdgcn_mfma_f32_16x16x32_bf16(kf, qa[0][ks], s0, 0, 0, 0);
                s1 = __builtin_amdgcn_mfma_f32_16x16x32_bf16(kf, qa[1][ks], s1, 0, 0, 0);
            }
            int cw = kb * 4 + g;
#pragma unroll
            for (int ib = 0; ib < 2; ++ib) {
                f32x4 sv = ib ? s1 : s0;
                unsigned mq = (unsigned)(m64[ib] >> (kb * 16 + g * 4)) & 15u;
                float p0 = (mq & 1u) ? __expf(sv[0]) : 0.f;
                float p1 = (mq & 2u) ? __expf(sv[1]) : 0.f;
                float p2 = (mq & 4u) ? __expf(sv[2]) : 0.f;
                float p3 = (mq & 8u) ? __expf(sv[3]) : 0.f;
                l2[ib] += (p0 + p1) + (p2 + p3);
                int q = ib * 16 + c15;
                US* wp = Pw + q * 64 + (((cw >> 1) ^ (q & 7)) * 8) + (cw & 1) * 4;
                us4 pv = { f2bf(p0), f2bf(p1), f2bf(p2), f2bf(p3) };
                *(us4*)wp = pv;
            }
        }

        // O^T += V^T P^T
#pragma unroll
        for (int ks = 0; ks < 2; ++ks) {
            bf16x8 pf[2];
#pragma unroll
            for (int ib = 0; ib < 2; ++ib) {
                int q = ib * 16 + c15;
                pf[ib] = ldv8(&Pw[q * 64 + (((ks * 4 + g) ^ (q & 7)) * 8)]);
            }
#pragma unroll
            for (int d = 0; d < 8; ++d) {
                bf16x8 vf = ldv8(&Vs[(d * 16 + c15) * 64 + (((ks * 4 + g) ^ (c15 & 7)) * 8)]);
                o[d][0] = __builtin_amdgcn_mfma_f32_16x16x32_bf16(vf, pf[0], o[d][0], 0, 0, 0);
                o[d][1] = __builtin_amdgcn_mfma_f32_16x16x32_bf16(vf, pf[1], o[d][1], 0, 0, 0);
            }
        }
    }

    // l: reduce over the 4 g-lanes sharing c15
    float lf[2];
#pragma unroll
    for (int ib = 0; ib < 2; ++ib) {
        float l = l2[ib];
        l += __shfl_xor(l, 16); l += __shfl_xor(l, 32);
        lf[ib] = l;
    }
    if (ln < 16) {
        size_t lb = ((size_t)sp * 32 + bh) * 512 + qbase + wq + c15;
        Lpart[lb] = lf[0];
        Lpart[lb + 16] = lf[1];
    }

    // epilogue: O^T regs -> q-major Opart [sp][bh][q 512][d 128] via per-wave LDS
    // transpose (Pw, per-wave so no barrier needed); full-line us8 stores.
    size_t obase = (((size_t)sp * 32 + bh) * 512 + qbase + wq) * 128;
#pragma unroll
    for (int half = 0; half < 2; ++half) {
#pragma unroll
        for (int d = 0; d < 4; ++d) {
            int dg = half * 4 + d;
            int c = d * 2 + (g >> 1), sub = g & 1;
#pragma unroll
            for (int ib = 0; ib < 2; ++ib) {
                int q = ib * 16 + c15;
                us4 pv = { f2bf(o[dg][ib][0]), f2bf(o[dg][ib][1]),
                           f2bf(o[dg][ib][2]), f2bf(o[dg][ib][3]) };
                *(us4*)&Pw[q * 64 + ((c ^ (q & 7)) * 8) + sub * 4] = pv;
            }
        }
#pragma unroll
        for (int p = 0; p < 4; ++p) {
            int q = p * 8 + (ln >> 3);
            int oct = ln & 7;
            us8 v = *(const us8*)&Pw[q * 64 + ((oct ^ (q & 7)) * 8)];
            *(us8*)(Opart + obase + (size_t)q * 128 + half * 64 + oct * 8) = v;
        }
    }
}

// ---------------- combine: q-major streaming sum of 6 splits -> AO bf16 ----------------
__global__ void combine(const US* __restrict__ Opart, const float* __restrict__ Lpart,
                        US* __restrict__ AO) {
    __shared__ float linv[128];
    const int qt = blockIdx.x, bh = blockIdx.y;
    const int b_ = bh >> 3, h = bh & 7;
    const int tid = threadIdx.x;
    const size_t spO = (size_t)32 * 512 * 128;
    const size_t spL = (size_t)32 * 512;

    if (tid < 128) {
        float s = 0.f;
#pragma unroll
        for (int sp = 0; sp < 6; ++sp)
            s += Lpart[sp * spL + (size_t)bh * 512 + qt * 128 + tid];
        linv[tid] = (s > 0.f) ? 1.f / s : 0.f;
    }
    __syncthreads();

#pragma unroll
    for (int p = 0; p < 8; ++p) {
        int ql = p * 16 + (tid >> 4);
        int d = (tid & 15) * 8;
        const US* base = Opart + ((size_t)bh * 512 + qt * 128 + ql) * 128 + d;
        float acc[8];
#pragma unroll
        for (int i = 0; i < 8; ++i) acc[i] = 0.f;
#pragma unroll
        for (int sp = 0; sp < 6; ++sp) {
            us8 v = *(const us8*)(base + sp * spO);
#pragma unroll
            for (int i = 0; i < 8; ++i) acc[i] += bf2f(v[i]);
        }
        float iv = linv[ql];
        us8 ov;
#pragma unroll
        for (int i = 0; i < 8; ++i) ov[i] = f2bf(acc[i] * iv);
        *(us8*)(AO + ((size_t)(b_ * 512 + qt * 128 + ql)) * 1024 + h * 128 + d) = ov;
    }
}

// ---------------- launch ----------------
extern "C" void kernel_launch(void* const* d_in, const int* in_sizes, int n_in,
                              void* d_out, int out_size, void* d_ws, size_t ws_size,
                              hipStream_t stream) {
    (void)in_sizes; (void)n_in; (void)out_size; (void)ws_size;
    const float* Xq  = (const float*)d_in[0];
    const float* Xkv = (const float*)d_in[1];
    const int*   Mi  = (const int*)d_in[2];
    const float* Wq  = (const float*)d_in[3];
    const float* bq  = (const float*)d_in[4];
    const float* Wk  = (const float*)d_in[5];
    const float* bk  = (const float*)d_in[6];
    const float* Wv  = (const float*)d_in[7];
    const float* bv  = (const float*)d_in[8];
    const float* Wo  = (const float*)d_in[9];
    const float* bo  = (const float*)d_in[10];
    float* out = (float*)d_out;

    // ws layout (aliasing is stream-order safe):
    char* p = (char*)d_ws;
    US* WT   = (US*)p; p += (size_t)4 * 1024 * 1024 * 2;     // 8.4 MB, live to end
    US* AO   = (US*)p; p += (size_t)2048 * 1024 * 2;         // 4.2 MB
    US* XqB  = (US*)p; p += (size_t)2048 * 1024 * 2;         // 4.2 MB, dead after Q-proj
    US* Qh   = (US*)p; p += (size_t)2048 * 1024 * 2;         // 4.2 MB
    US* Kh   = (US*)p; p += (size_t)16384 * 1024 * 2;        // 33.5 MB
    US* VTh  = (US*)p; p += (size_t)16384 * 1024 * 2;        // 33.5 MB
    US* XkvB = (US*)p; p += (size_t)16384 * 1024 * 2;        // 33.5 MB, dead after gemm_kv
    unsigned long long* MBits = (unsigned long long*)p; p += (size_t)131072 * 8;  // 1 MB
    US* Opart    = XkvB;           // 25.2 MB bf16 partials [6][32][512][128] in XkvB
    float* Lpart = (float*)XqB;    // 393 KB; XqB dead after Q-proj

    prep<<<4096, 256, 0, stream>>>(Xq, Xkv, Mi, MBits, XqB, XkvB, Wq, Wk, Wv, Wo, WT);

    // Q projection: fold softmax scale 1/sqrt(128) into Q
    gemm_bt<0, 64><<<dim3(32, 8), 256, 0, stream>>>(XqB, WT, bq, Qh, 9, 0.08838834764831843f);
    gemm_kv<<<dim3(128, 8), 256, 0, stream>>>(XkvB, WT + 1048576, WT + 2097152,
                                              bk, bv, Kh, VTh);
    flash<<<768, 256, 0, stream>>>(Qh, Kh, VTh, MBits, Opart, Lpart);
    combine<<<dim3(4, 32), 256, 0, stream>>>(Opart, Lpart, AO);
    gemm_bt<1, 64><<<dim3(32, 8), 256, 0, stream>>>(AO, WT + 3145728, bo, out, 0, 1.0f);
}

// Round 11
// 323.462 us; speedup vs baseline: 1.3489x; 1.0948x over previous
//
#include <hip/hip_runtime.h>
#include <cstdint>
#include <cstddef>

typedef unsigned short US;
typedef __bf16 bf16_t;
typedef bf16_t bf16x8 __attribute__((ext_vector_type(8)));
typedef float  f32x4  __attribute__((ext_vector_type(4)));
typedef US     us8    __attribute__((ext_vector_type(8)));
typedef US     us4    __attribute__((ext_vector_type(4)));

#define AS1 __attribute__((address_space(1)))
#define AS3 __attribute__((address_space(3)))

__device__ __forceinline__ void gl_lds16(const void* g, void* l) {
    __builtin_amdgcn_global_load_lds((AS1 unsigned int*)(size_t)g,
                                     (AS3 unsigned int*)l, 16, 0, 0);
}

__device__ __forceinline__ US f2bf(float f) {
    unsigned u = __builtin_bit_cast(unsigned, f);
    u += 0x7FFFu + ((u >> 16) & 1u);   // RNE (inputs finite)
    return (US)(u >> 16);
}

__device__ __forceinline__ float bf2f(US u) {
    return __builtin_bit_cast(float, (unsigned)u << 16);
}

__device__ __forceinline__ bf16x8 ldv8(const US* p) {
    return __builtin_bit_cast(bf16x8, *(const us8*)p);
}

// ---------------- prep: X converts + mask bits + weight transposes (4096 fat blocks) ----
// All roles HBM-streaming (L2-safe to fuse; never fuse streaming with GEMMs — r6).
// Mask layout [b][q][kt]: per-lane line holds 8 consecutive kv-tiles (L1 reuse in flash).
__global__ void prep(const float* __restrict__ Xq, const float* __restrict__ Xkv,
                     const int* __restrict__ Mi, unsigned long long* __restrict__ MBits,
                     US* __restrict__ XqB, US* __restrict__ XkvB,
                     const float* __restrict__ Wq, const float* __restrict__ Wk,
                     const float* __restrict__ Wv, const float* __restrict__ Wo,
                     US* __restrict__ WTbase) {
    __shared__ float t[32][33];
    const int b = blockIdx.x, tid = threadIdx.x;

    for (int u = b; u < 18432; u += 4096) {
        if (u < 2048) {
            int i = u * 256 + tid;
            float4 f = ((const float4*)Xq)[i];
            us4 o = { f2bf(f.x), f2bf(f.y), f2bf(f.z), f2bf(f.w) };
            ((us4*)XqB)[i] = o;
        } else {
            int i = (u - 2048) * 256 + tid;
            float4 f = ((const float4*)Xkv)[i];
            us4 o = { f2bf(f.x), f2bf(f.y), f2bf(f.z), f2bf(f.w) };
            ((us4*)XkvB)[i] = o;
        }
    }

    for (int u = b; u < 32768; u += 4096) {
        int i = u * 256 + tid;                 // wave = 64 consecutive kv of one (b,q)
        int m = Mi[i];
        unsigned long long bits = __ballot(m != 0);
        if ((tid & 63) == 0) MBits[i >> 6] = bits;
    }

    {
        int z = b >> 10, rr = b & 1023;
        int bx = rr & 31, by = rr >> 5;
        const float* W = (z == 0) ? Wq : (z == 1) ? Wk : (z == 2) ? Wv : Wo;
        US* WT = WTbase + (size_t)z * 1024 * 1024;
        int tx = tid & 31, ty = tid >> 5;
        int x = bx * 32 + tx;
#pragma unroll
        for (int r = 0; r < 4; ++r)
            t[ty + r * 8][tx] = W[(size_t)(by * 32 + ty + r * 8) * 1024 + x];
        __syncthreads();
        int nx = by * 32 + tx;
#pragma unroll
        for (int r = 0; r < 4; ++r)
            WT[(size_t)(bx * 32 + ty + r * 8) * 1024 + nx] = f2bf(t[tx][ty + r * 8]);
    }
}

// ---------------- O-projection GEMM: out[2048,1024] fp32 = AO @ Wo^T + bo -------------
__global__ __launch_bounds__(256, 2)
void gemm_o(const US* __restrict__ A, const US* __restrict__ Bt,
            const float* __restrict__ bias, float* __restrict__ out) {
    constexpr int K = 1024, N = 1024, BK = 64, BM = 64;
    __shared__ US As[BM * BK];
    __shared__ US Bs[128 * BK];
    const int tid = threadIdx.x;
    const int wv = tid >> 6, ln = tid & 63;
    const int g = ln >> 4, c15 = ln & 15;
    const int m0 = blockIdx.x * BM, n0 = blockIdx.y * 128;
    const int wm = (wv & 1) * 32, wn = (wv >> 1) * 64;

    f32x4 acc[2][4];
    const f32x4 z = {0.f, 0.f, 0.f, 0.f};
#pragma unroll
    for (int i = 0; i < 2; ++i)
#pragma unroll
        for (int j = 0; j < 4; ++j) acc[i][j] = z;

    const US* Ab = A + (size_t)m0 * K;
    const US* Bb = Bt + (size_t)n0 * K;

    for (int k0 = 0; k0 < K; k0 += BK) {
        __syncthreads();
#pragma unroll
        for (int q = 0; q < 2; ++q) {
            int eb = (q * 256 + wv * 64) * 8;
            int r = (eb >> 6) + (ln >> 3);
            int sw = (ln & 7) ^ (r & 7);
            gl_lds16(Ab + (size_t)r * K + k0 + sw * 8, &As[eb]);
        }
#pragma unroll
        for (int q = 0; q < 4; ++q) {
            int eb = (q * 256 + wv * 64) * 8;
            int r = (eb >> 6) + (ln >> 3);
            int sw = (ln & 7) ^ (r & 7);
            gl_lds16(Bb + (size_t)r * K + k0 + sw * 8, &Bs[eb]);
        }
        __syncthreads();
#pragma unroll
        for (int ks = 0; ks < 2; ++ks) {
            bf16x8 a[2], b[4];
#pragma unroll
            for (int i = 0; i < 2; ++i) {
                int p = (ks * 4 + g) ^ (c15 & 7);
                a[i] = ldv8(&As[(wm + i * 16 + c15) * BK + p * 8]);
            }
#pragma unroll
            for (int j = 0; j < 4; ++j) {
                int p = (ks * 4 + g) ^ (c15 & 7);
                b[j] = ldv8(&Bs[(wn + j * 16 + c15) * BK + p * 8]);
            }
#pragma unroll
            for (int i = 0; i < 2; ++i)
#pragma unroll
                for (int j = 0; j < 4; ++j)
                    acc[i][j] = __builtin_amdgcn_mfma_f32_16x16x32_bf16(a[i], b[j], acc[i][j], 0, 0, 0);
        }
    }

#pragma unroll
    for (int i = 0; i < 2; ++i)
#pragma unroll
        for (int j = 0; j < 4; ++j) {
            int col = n0 + wn + j * 16 + c15;
            float bvv = bias[col];
#pragma unroll
            for (int r = 0; r < 4; ++r) {
                int row = m0 + wm + i * 16 + g * 4 + r;
                out[(size_t)row * N + col] = acc[i][j][r] + bvv;
            }
        }
}

// ---------------- fused K+V+Q projection GEMM (1280 blocks, role by range) ------------
// bid < 1024: K/V tiles (r7 order: m = bid&127, n = bid>>7); V written pre-transposed.
// bid >= 1024: Q-projection BM=64 tiles (r6-verified role) — tail-fills the drain slots.
// Homogeneous GEMM+GEMM fusion: Q-role touches only ~6 MB, no L2 pollution (unlike r6's
// streaming-mask fusion).
__global__ __launch_bounds__(256, 2)
void gemm_kvq(const US* __restrict__ A, const US* __restrict__ XqB,
              const US* __restrict__ BtK, const US* __restrict__ BtV,
              const US* __restrict__ BtQ, const float* __restrict__ bk,
              const float* __restrict__ bv, const float* __restrict__ bq,
              US* __restrict__ Kout, US* __restrict__ VTout, US* __restrict__ Qh) {
    constexpr int K = 1024, BK = 64;
    __shared__ US lds[3 * 128 * BK];
    const int bid = blockIdx.x;
    const int tid = threadIdx.x;
    const int wv = tid >> 6, ln = tid & 63;
    const int g = ln >> 4, c15 = ln & 15;
    const f32x4 z = {0.f, 0.f, 0.f, 0.f};

    if (bid >= 1024) {
        // ---- Q-projection role: BM=64 tile of Q = XqB @ Wq^T, scaled ----
        int idx = bid - 1024;                   // 0..255
        const int m0 = (idx & 31) * 64, n0 = (idx >> 5) * 128;
        const int wm = (wv & 1) * 32, wn = (wv >> 1) * 64;
        US* As = lds;                           // 64 x 64
        US* Bs = lds + 64 * 64;                 // 128 x 64
        f32x4 acc[2][4];
#pragma unroll
        for (int i = 0; i < 2; ++i)
#pragma unroll
            for (int j = 0; j < 4; ++j) acc[i][j] = z;
        const US* Ab = XqB + (size_t)m0 * K;
        const US* Bb = BtQ + (size_t)n0 * K;
        for (int k0 = 0; k0 < K; k0 += BK) {
            __syncthreads();
#pragma unroll
            for (int q = 0; q < 2; ++q) {
                int eb = (q * 256 + wv * 64) * 8;
                int r = (eb >> 6) + (ln >> 3);
                int sw = (ln & 7) ^ (r & 7);
                gl_lds16(Ab + (size_t)r * K + k0 + sw * 8, &As[eb]);
            }
#pragma unroll
            for (int q = 0; q < 4; ++q) {
                int eb = (q * 256 + wv * 64) * 8;
                int r = (eb >> 6) + (ln >> 3);
                int sw = (ln & 7) ^ (r & 7);
                gl_lds16(Bb + (size_t)r * K + k0 + sw * 8, &Bs[eb]);
            }
            __syncthreads();
#pragma unroll
            for (int ks = 0; ks < 2; ++ks) {
                bf16x8 a[2], b[4];
#pragma unroll
                for (int i = 0; i < 2; ++i) {
                    int p = (ks * 4 + g) ^ (c15 & 7);
                    a[i] = ldv8(&As[(wm + i * 16 + c15) * BK + p * 8]);
                }
#pragma unroll
                for (int j = 0; j < 4; ++j) {
                    int p = (ks * 4 + g) ^ (c15 & 7);
                    b[j] = ldv8(&Bs[(wn + j * 16 + c15) * BK + p * 8]);
                }
#pragma unroll
                for (int i = 0; i < 2; ++i)
#pragma unroll
                    for (int j = 0; j < 4; ++j)
                        acc[i][j] = __builtin_amdgcn_mfma_f32_16x16x32_bf16(a[i], b[j], acc[i][j], 0, 0, 0);
            }
        }
        const float scale = 0.08838834764831843f;   // 1/sqrt(128) folded into Q
#pragma unroll
        for (int i = 0; i < 2; ++i) {
#pragma unroll
            for (int j = 0; j < 4; ++j) {
                int col = n0 + wn + j * 16 + c15;
                float bvv = bq[col];
                int h = col >> 7, d = col & 127;
#pragma unroll
                for (int r = 0; r < 4; ++r) {
                    int row = m0 + wm + i * 16 + g * 4 + r;
                    int b_ = row >> 9, tq = row & 511;
                    Qh[(((size_t)(b_ * 8 + h) << 9) + tq) * 128 + d] =
                        f2bf((acc[i][j][r] + bvv) * scale);
                }
            }
        }
        return;
    }

    // ---- K+V projection role (1024 blocks, r7 order) ----
    US* As  = lds;
    US* BsK = lds + 128 * BK;
    US* BsV = lds + 2 * 128 * BK;
    const int m0 = (bid & 127) * 128, n0 = (bid >> 7) * 128;
    const int wm = (wv & 1) * 64, wn = (wv >> 1) * 64;

    f32x4 aK[4][4], aV[4][4];
#pragma unroll
    for (int i = 0; i < 4; ++i)
#pragma unroll
        for (int j = 0; j < 4; ++j) { aK[i][j] = z; aV[i][j] = z; }

    const US* Ab  = A   + (size_t)m0 * K;
    const US* BbK = BtK + (size_t)n0 * K;
    const US* BbV = BtV + (size_t)n0 * K;

    for (int k0 = 0; k0 < K; k0 += BK) {
        __syncthreads();
#pragma unroll
        for (int q = 0; q < 4; ++q) {
            int eb = (q * 256 + wv * 64) * 8;
            int r = (eb >> 6) + (ln >> 3);
            int sw = (ln & 7) ^ (r & 7);
            gl_lds16(Ab  + (size_t)r * K + k0 + sw * 8, &As[eb]);
            gl_lds16(BbK + (size_t)r * K + k0 + sw * 8, &BsK[eb]);
            gl_lds16(BbV + (size_t)r * K + k0 + sw * 8, &BsV[eb]);
        }
        __syncthreads();
#pragma unroll
        for (int ks = 0; ks < 2; ++ks) {
            bf16x8 a[4], bK[4], bV[4];
#pragma unroll
            for (int i = 0; i < 4; ++i) {
                int p = (ks * 4 + g) ^ (c15 & 7);
                a[i] = ldv8(&As[(wm + i * 16 + c15) * BK + p * 8]);
            }
#pragma unroll
            for (int j = 0; j < 4; ++j) {
                int p = (ks * 4 + g) ^ (c15 & 7);
                bK[j] = ldv8(&BsK[(wn + j * 16 + c15) * BK + p * 8]);
                bV[j] = ldv8(&BsV[(wn + j * 16 + c15) * BK + p * 8]);
            }
#pragma unroll
            for (int i = 0; i < 4; ++i)
#pragma unroll
                for (int j = 0; j < 4; ++j) {
                    aK[i][j] = __builtin_amdgcn_mfma_f32_16x16x32_bf16(a[i], bK[j], aK[i][j], 0, 0, 0);
                    aV[i][j] = __builtin_amdgcn_mfma_f32_16x16x32_bf16(a[i], bV[j], aV[i][j], 0, 0, 0);
                }
        }
    }

    const int h = n0 >> 7;
    const int b_ = m0 >> 12, tbase = m0 & 4095;

    // K epilogue: split-heads bf16 store
#pragma unroll
    for (int i = 0; i < 4; ++i) {
#pragma unroll
        for (int j = 0; j < 4; ++j) {
            int col = n0 + wn + j * 16 + c15;
            float bkv = bk[col];
            int d = col & 127;
#pragma unroll
            for (int r = 0; r < 4; ++r) {
                int row = m0 + wm + i * 16 + g * 4 + r;
                int t = row & 4095;
                Kout[(((size_t)(b_ * 8 + h) << 12) + t) * 128 + d] = f2bf(aK[i][j][r] + bkv);
            }
        }
    }

    // V epilogue: transpose through LDS, write VT rows (coalesced)
    __syncthreads();
    US* T = lds;                                // [d 128][kv 128], stride 136
#pragma unroll
    for (int i = 0; i < 4; ++i) {
#pragma unroll
        for (int j = 0; j < 4; ++j) {
            int dcol = wn + j * 16 + c15;
            float bvv = bv[n0 + dcol];
#pragma unroll
            for (int r = 0; r < 4; ++r) {
                int kvrow = wm + i * 16 + g * 4 + r;
                T[dcol * 136 + kvrow] = f2bf(aV[i][j][r] + bvv);
            }
        }
    }
    __syncthreads();
    {
        int d = tid >> 1, half = (tid & 1) * 64;
        US* vrow = VTout + ((size_t)(b_ * 8 + h) * 128 + d) * 4096 + tbase + half;
        const US* tr = &T[d * 136 + half];
#pragma unroll
        for (int s = 0; s < 8; ++s)
            *(us8*)(vrow + s * 8) = *(const us8*)(tr + s * 8);
    }
}

// ---------------- flash attention (exact round-7 shape): S^T, split-KV, bitmask --------
// 1-D grid of 768: id = qt*192 + bh*6 + sp -> qt-siblings same XCD. 4 waves x 32 q.
__global__ __launch_bounds__(256, 3)
void flash(const US* __restrict__ Qh, const US* __restrict__ Kh,
           const US* __restrict__ VTh, const unsigned long long* __restrict__ MBits,
           US* __restrict__ Opart, float* __restrict__ Lpart) {
    __shared__ US Ks[64 * 128];        // [kv][d] 16KB, swz (r&15)
    __shared__ US Vs[128 * 64];        // [d][kv] 16KB, swz (r&7)
    __shared__ US Ps[4][32 * 64];      // per-wave P [q32][kv64] 16KB, chunk swz (q&7)
    const int tid = threadIdx.x, wv = tid >> 6, ln = tid & 63;
    const int g = ln >> 4, c15 = ln & 15;
    const int bid = blockIdx.x;
    const int qt = bid / 192;
    const int rest = bid - qt * 192;
    const int bh = rest / 6, sp = rest - bh * 6;
    const int qbase = qt * 128;
    const int b_ = bh >> 3;
    const int t0 = (sp < 4) ? sp * 11 : 44 + (sp - 4) * 10;   // tiles of 64 kv
    const int nt = (sp < 4) ? 11 : 10;
    const int wq = wv * 32;

    bf16x8 qa[2][4];
#pragma unroll
    for (int ib = 0; ib < 2; ++ib) {
        const US* qrow = Qh + ((size_t)bh * 512 + qbase + wq + ib * 16 + c15) * 128;
#pragma unroll
        for (int ks = 0; ks < 4; ++ks)
            qa[ib][ks] = ldv8(qrow + ks * 32 + g * 8);
    }

    f32x4 o[8][2];
    const f32x4 z = {0.f, 0.f, 0.f, 0.f};
#pragma unroll
    for (int d = 0; d < 8; ++d) { o[d][0] = z; o[d][1] = z; }
    float l2[2] = {0.f, 0.f};

    const unsigned long long* Mrow[2];
    Mrow[0] = MBits + (size_t)(b_ * 512 + qbase + wq + c15) * 64;
    Mrow[1] = Mrow[0] + (size_t)16 * 64;
    const US* Kbase = Kh + ((size_t)bh * 4096 + (size_t)t0 * 64) * 128;
    const US* Vbase = VTh + (size_t)bh * 128 * 4096;
    US* Pw = &Ps[wv][0];

    for (int t = 0; t < nt; ++t) {
        int kv0 = (t0 + t) * 64;
        __syncthreads();
        const US* Kb = Kbase + (size_t)t * 64 * 128;
#pragma unroll
        for (int q = 0; q < 4; ++q) {               // K tile
            int eb = (q * 256 + wv * 64) * 8;
            int r = (eb >> 7) + (ln >> 4);
            int sw = (ln & 15) ^ (r & 15);
            gl_lds16(Kb + (size_t)r * 128 + sw * 8, &Ks[eb]);
        }
#pragma unroll
        for (int q = 0; q < 4; ++q) {               // V^T tile
            int eb = (q * 256 + wv * 64) * 8;
            int r = (eb >> 6) + (ln >> 3);
            int sw = (ln & 7) ^ (r & 7);
            gl_lds16(Vbase + (size_t)r * 4096 + kv0 + sw * 8, &Vs[eb]);
        }
        unsigned long long m64[2];
        m64[0] = Mrow[0][t0 + t];
        m64[1] = Mrow[1][t0 + t];
        __syncthreads();

        // S^T per kb: 16 kv x 32 q, then exp/mask -> P LDS
#pragma unroll
        for (int kb = 0; kb < 4; ++kb) {
            f32x4 s0 = z, s1 = z;
#pragma unroll
            for (int ks = 0; ks < 4; ++ks) {
                bf16x8 kf = ldv8(&Ks[(kb * 16 + c15) * 128 + (((ks * 4 + g) ^ c15) * 8)]);
                s0 = __builtin_amdgcn_mfma_f32_16x16x32_bf16(kf, qa[0][ks], s0, 0, 0, 0);
                s1 = __builtin_amdgcn_mfma_f32_16x16x32_bf16(kf, qa[1][ks], s1, 0, 0, 0);
            }
            int cw = kb * 4 + g;
#pragma unroll
            for (int ib = 0; ib < 2; ++ib) {
                f32x4 sv = ib ? s1 : s0;
                unsigned mq = (unsigned)(m64[ib] >> (kb * 16 + g * 4)) & 15u;
                float p0 = (mq & 1u) ? __expf(sv[0]) : 0.f;
                float p1 = (mq & 2u) ? __expf(sv[1]) : 0.f;
                float p2 = (mq & 4u) ? __expf(sv[2]) : 0.f;
                float p3 = (mq & 8u) ? __expf(sv[3]) : 0.f;
                l2[ib] += (p0 + p1) + (p2 + p3);
                int q = ib * 16 + c15;
                US* wp = Pw + q * 64 + (((cw >> 1) ^ (q & 7)) * 8) + (cw & 1) * 4;
                us4 pv = { f2bf(p0), f2bf(p1), f2bf(p2), f2bf(p3) };
                *(us4*)wp = pv;
            }
        }

        // O^T += V^T P^T
#pragma unroll
        for (int ks = 0; ks < 2; ++ks) {
            bf16x8 pf[2];
#pragma unroll
            for (int ib = 0; ib < 2; ++ib) {
                int q = ib * 16 + c15;
                pf[ib] = ldv8(&Pw[q * 64 + (((ks * 4 + g) ^ (q & 7)) * 8)]);
            }
#pragma unroll
            for (int d = 0; d < 8; ++d) {
                bf16x8 vf = ldv8(&Vs[(d * 16 + c15) * 64 + (((ks * 4 + g) ^ (c15 & 7)) * 8)]);
                o[d][0] = __builtin_amdgcn_mfma_f32_16x16x32_bf16(vf, pf[0], o[d][0], 0, 0, 0);
                o[d][1] = __builtin_amdgcn_mfma_f32_16x16x32_bf16(vf, pf[1], o[d][1], 0, 0, 0);
            }
        }
    }

    float lf[2];
#pragma unroll
    for (int ib = 0; ib < 2; ++ib) {
        float l = l2[ib];
        l += __shfl_xor(l, 16); l += __shfl_xor(l, 32);
        lf[ib] = l;
    }
    if (ln < 16) {
        size_t lb = ((size_t)sp * 32 + bh) * 512 + qbase + wq + c15;
        Lpart[lb] = lf[0];
        Lpart[lb + 16] = lf[1];
    }
    // Opart [sp][bh][d=128][q=512], un-normalized bf16 partials (r7 layout)
    US* Ob = Opart + (((size_t)sp * 32 + bh) * 128 + g * 4) * 512 + qbase + wq + c15;
#pragma unroll
    for (int d = 0; d < 8; ++d)
#pragma unroll
        for (int r = 0; r < 4; ++r) {
            Ob[(size_t)(d * 16 + r) * 512] = f2bf(o[d][0][r]);
            Ob[(size_t)(d * 16 + r) * 512 + 16] = f2bf(o[d][1][r]);
        }
}

// ---------------- combine: sum 6 bf16 splits, normalize, transpose -> AO bf16 ----------
__global__ void combine(const US* __restrict__ Opart, const float* __restrict__ Lpart,
                        US* __restrict__ AO) {
    __shared__ float linv[128];
    __shared__ float T[128 * 33];
    const int qt = blockIdx.x, bh = blockIdx.y;
    const int b_ = bh >> 3, h = bh & 7;
    const int tid = threadIdx.x;
    const size_t spstride = (size_t)32 * 128 * 512;

    if (tid < 128) {
        float s = 0.f;
#pragma unroll
        for (int sp = 0; sp < 6; ++sp)
            s += Lpart[((size_t)sp * 32 + bh) * 512 + qt * 128 + tid];
        linv[tid] = (s > 0.f) ? 1.f / s : 0.f;
    }
    __syncthreads();

    for (int ds0 = 0; ds0 < 128; ds0 += 32) {
        if (ds0) __syncthreads();
        {
            int d = ds0 + (tid >> 3);
            int q0 = (tid & 7) * 16;
            const US* base = Opart + ((size_t)bh * 128 + d) * 512 + qt * 128 + q0;
            float acc[16];
#pragma unroll
            for (int i = 0; i < 16; ++i) acc[i] = 0.f;
#pragma unroll
            for (int sp = 0; sp < 6; ++sp) {
                us8 a = *(const us8*)(base + sp * spstride);
                us8 b = *(const us8*)(base + sp * spstride + 8);
#pragma unroll
                for (int i = 0; i < 8; ++i) {
                    acc[i] += bf2f(a[i]);
                    acc[8 + i] += bf2f(b[i]);
                }
            }
            int dd = d - ds0;
#pragma unroll
            for (int i = 0; i < 16; ++i)
                T[(q0 + i) * 33 + dd] = acc[i] * linv[q0 + i];
        }
        __syncthreads();
#pragma unroll
        for (int it = 0; it < 4; ++it) {
            int idx = tid + it * 256;
            int q = idx >> 3, c = idx & 7;
            const float* tr = &T[q * 33 + c * 4];
            us4 ov = { f2bf(tr[0]), f2bf(tr[1]), f2bf(tr[2]), f2bf(tr[3]) };
            *(us4*)(AO + ((size_t)(b_ * 512 + qt * 128 + q)) * 1024 + h * 128 + ds0 + c * 4) = ov;
        }
    }
}

// ---------------- launch ----------------
extern "C" void kernel_launch(void* const* d_in, const int* in_sizes, int n_in,
                              void* d_out, int out_size, void* d_ws, size_t ws_size,
                              hipStream_t stream) {
    (void)in_sizes; (void)n_in; (void)out_size; (void)ws_size;
    const float* Xq  = (const float*)d_in[0];
    const float* Xkv = (const float*)d_in[1];
    const int*   Mi  = (const int*)d_in[2];
    const float* Wq  = (const float*)d_in[3];
    const float* bq  = (const float*)d_in[4];
    const float* Wk  = (const float*)d_in[5];
    const float* bk  = (const float*)d_in[6];
    const float* Wv  = (const float*)d_in[7];
    const float* bv  = (const float*)d_in[8];
    const float* Wo  = (const float*)d_in[9];
    const float* bo  = (const float*)d_in[10];
    float* out = (float*)d_out;

    // ws layout (aliasing is stream-order safe):
    char* p = (char*)d_ws;
    US* WT   = (US*)p; p += (size_t)4 * 1024 * 1024 * 2;     // 8.4 MB, live to end
    US* AO   = (US*)p; p += (size_t)2048 * 1024 * 2;         // 4.2 MB
    US* XqB  = (US*)p; p += (size_t)2048 * 1024 * 2;         // 4.2 MB, dead after gemm_kvq
    US* Qh   = (US*)p; p += (size_t)2048 * 1024 * 2;         // 4.2 MB
    US* Kh   = (US*)p; p += (size_t)16384 * 1024 * 2;        // 33.5 MB
    US* VTh  = (US*)p; p += (size_t)16384 * 1024 * 2;        // 33.5 MB
    US* XkvB = (US*)p; p += (size_t)16384 * 1024 * 2;        // 33.5 MB, dead after gemm_kvq
    unsigned long long* MBits = (unsigned long long*)p; p += (size_t)131072 * 8;  // 1 MB
    US* Opart    = XkvB;           // 25.2 MB bf16 partials [6][32][128][512] in XkvB
    float* Lpart = (float*)XqB;    // 393 KB; XqB dead after gemm_kvq

    prep<<<4096, 256, 0, stream>>>(Xq, Xkv, Mi, MBits, XqB, XkvB, Wq, Wk, Wv, Wo, WT);

    gemm_kvq<<<1280, 256, 0, stream>>>(XkvB, XqB, WT + 1048576, WT + 2097152, WT,
                                       bk, bv, bq, Kh, VTh, Qh);
    flash<<<768, 256, 0, stream>>>(Qh, Kh, VTh, MBits, Opart, Lpart);
    combine<<<dim3(4, 32), 256, 0, stream>>>(Opart, Lpart, AO);
    gemm_o<<<dim3(32, 8), 256, 0, stream>>>(AO, WT + 3145728, bo, out);
}